// Round 3
// 1049.847 us; speedup vs baseline: 1.0546x; 1.0546x over previous
//
#include <hip/hip_runtime.h>
#include <hip/hip_bf16.h>
#include <cmath>

#define TBL (1 << 19)   // T = 2^19 hash table entries per level (power of two)

__device__ __forceinline__ float relu_f(float x) { return fmaxf(x, 0.0f); }

// fp32 -> bf16 bits, round-to-nearest-even
__device__ __forceinline__ unsigned short f2bf(float x) {
    union { float f; unsigned u; } v; v.f = x;
    const unsigned r = v.u + 0x7FFFu + ((v.u >> 16) & 1u);
    return (unsigned short)(r >> 16);
}

typedef __attribute__((ext_vector_type(8))) short short8;   // 8 bf16 = 4 VGPRs (A/B frag)
typedef __attribute__((ext_vector_type(4))) float floatx4;  // C/D frag

// res_l = floor(16 * 1.3819^l); dense iff (res+1)^3 <= 2^19  (l = 0..4)
#define RES_LIST {16, 22, 30, 42, 58, 80, 111, 153, 212, 294, 406, 561, 775, 1072, 1481, 2047}

// ---------------------------------------------------------------------------
// Single-dispatch scheduled encode.
//   - blockIdx%8 selects the XCD (round-robin dispatch).
//   - Each XCD runs 8 sequential quarter-units (level, quarter-of-points).
//     Hashed levels split across TWO XCDs (2x L2 slice BW per level); dense
//     levels fill the remainder. Load balance weight hashed 1.5 : dense 1.0.
//   - Hashed corner pairing: PRIMES[0]==1 so for even x0,
//     idx(x0+1) = idx(x0)^1 -> both entries in one ALIGNED 16B slot -> float4.
//     Odd x0 falls back to two float2 loads. Dense path: two aligned float2
//     loads per x-pair.
//
// Schedule tables packed as constexpr bitfields (unit 0 = low bits); verified
// by hand: all 64 (level, quarter) units appear exactly once.
// ---------------------------------------------------------------------------
__global__ __launch_bounds__(256, 8)
void encode_sched(const float* __restrict__ xyz,
                  const float* __restrict__ table,
                  float* __restrict__ ws_enc,      // float2 slots [level*n + i]
                  int n)
{
    constexpr unsigned RES[16] = RES_LIST;
    constexpr unsigned LEVP[8] = {0x00665555u, 0x00777766u, 0x11998888u, 0x11AAAA99u,
                                  0x222CBBBBu, 0x332DDCCCu, 0x433EEEDDu, 0x444FFFFEu};
    constexpr unsigned QTRP[8] = {0x44E4u, 0xEE4Eu, 0x44E4u, 0xEE4Eu,
                                  0x90E4u, 0x4D39u, 0x3A4Eu, 0xE793u};

    const int xcd      = (int)(blockIdx.x & 7u);
    const unsigned g   = blockIdx.x >> 3;
    const unsigned upb = (unsigned)(n >> 10);     // blocks per quarter-unit
    const int unit     = (int)(g / upb);
    const int slot     = (int)(g % upb);
    const int level    = (int)((LEVP[xcd] >> (4 * unit)) & 15u);
    const int quarter  = (int)((QTRP[xcd] >> (2 * unit)) & 3u);
    const int i        = quarter * (n >> 2) + slot * 256 + (int)threadIdx.x;
    if (i >= n) return;

    const float px_ = __builtin_nontemporal_load(xyz + 3 * (size_t)i + 0);
    const float py_ = __builtin_nontemporal_load(xyz + 3 * (size_t)i + 1);
    const float pz_ = __builtin_nontemporal_load(xyz + 3 * (size_t)i + 2);

    const unsigned res = RES[level];
    const float fr = (float)res;
    const float posx = px_ * fr, posy = py_ * fr, posz = pz_ * fr;
    const float fx = floorf(posx), fy = floorf(posy), fz = floorf(posz);
    const float wx = posx - fx, wy = posy - fy, wz = posz - fz;
    const unsigned x0 = (unsigned)fx, y0 = (unsigned)fy, z0 = (unsigned)fz;
    const float* tb = table + (size_t)level * (TBL * 2);

    float a0 = 0.0f, a1 = 0.0f;
    const float wx1 = wx, wx0 = 1.0f - wx;

    if (level < 5) {
        const unsigned s = res + 1u;
        const unsigned s2 = s * s;
        const unsigned base = x0 + y0 * s + z0 * s2;
#pragma unroll
        for (int c = 0; c < 4; ++c) {
            const unsigned dy = c & 1, dz = c >> 1;
            const unsigned idx = base + dy * s + dz * s2;
            const float wyz = (dy ? wy : 1.0f - wy) * (dz ? wz : 1.0f - wz);
            const float w0 = wyz * wx0, w1 = wyz * wx1;
            const float2 f0 = *reinterpret_cast<const float2*>(tb + 2u * idx);
            const float2 f1 = *reinterpret_cast<const float2*>(tb + 2u * idx + 2u);
            a0 = fmaf(f0.x, w0, fmaf(f1.x, w1, a0));
            a1 = fmaf(f0.y, w0, fmaf(f1.y, w1, a1));
        }
    } else {
#pragma unroll
        for (int c = 0; c < 4; ++c) {
            const unsigned dy = c & 1, dz = c >> 1;
            const unsigned hh = (y0 + dy) * 2654435761u ^ (z0 + dz) * 805459861u;
            const float wyz = (dy ? wy : 1.0f - wy) * (dz ? wz : 1.0f - wz);
            const float w0 = wyz * wx0, w1 = wyz * wx1;
            const unsigned i0 = (x0 ^ hh) & (unsigned)(TBL - 1);
            if (!(x0 & 1u)) {
                // x0 even: idx(x0+1) = i0^1 -> one aligned 16B slot
                const float4 f = *reinterpret_cast<const float4*>(tb + 2u * (i0 & ~1u));
                const bool hi = (i0 & 1u) != 0u;       // position of the x0 entry
                const float e0x = hi ? f.z : f.x, e0y = hi ? f.w : f.y;
                const float e1x = hi ? f.x : f.z, e1y = hi ? f.y : f.w;
                a0 = fmaf(e0x, w0, fmaf(e1x, w1, a0));
                a1 = fmaf(e0y, w0, fmaf(e1y, w1, a1));
            } else {
                const unsigned i1 = ((x0 + 1u) ^ hh) & (unsigned)(TBL - 1);
                const float2 f0 = *reinterpret_cast<const float2*>(tb + 2u * i0);
                const float2 f1 = *reinterpret_cast<const float2*>(tb + 2u * i1);
                a0 = fmaf(f0.x, w0, fmaf(f1.x, w1, a0));
                a1 = fmaf(f0.y, w0, fmaf(f1.y, w1, a1));
            }
        }
    }

    float* dst = ws_enc + 2 * ((size_t)level * n + i);
    __builtin_nontemporal_store(a0, dst + 0);
    __builtin_nontemporal_store(a1, dst + 1);
}

// ---------------------------------------------------------------------------
// MFMA MLP (unchanged). Block = 256 thr = 4 waves; wave owns 64 points.
// ---------------------------------------------------------------------------
__global__ __launch_bounds__(256)
void mlp_mfma(const float* __restrict__ ws_enc,
              const float* __restrict__ dirv,
              const float* __restrict__ ws1,   // (32,64)
              const float* __restrict__ ws2,   // (64,17)
              const float* __restrict__ wr1,   // (32,64)
              const float* __restrict__ wr2,   // (64,64)
              const float* __restrict__ wr3,   // (64,3)
              float* __restrict__ out,
              int n)
{
    __shared__ alignas(16) unsigned short s_w[13184];
    __shared__ alignas(16) unsigned short s_act[4 * 16 * 72];
    __shared__ alignas(16) float          s_geo[4 * 16 * 20];

    const int tid = threadIdx.x;

    for (int e = tid; e < 13184; e += 256) s_w[e] = 0;
    __syncthreads();
    for (int e = tid; e < 2048; e += 256) { const int k = e >> 6, j = e & 63; s_w[0     + j * 40 + k] = f2bf(ws1[e]); }
    for (int e = tid; e < 1088; e += 256) { const int k = e / 17, j = e % 17; s_w[2560  + j * 72 + k] = f2bf(ws2[e]); }
    for (int e = tid; e < 2048; e += 256) { const int k = e >> 6, j = e & 63; s_w[4864  + j * 40 + k] = f2bf(wr1[e]); }
    for (int e = tid; e < 4096; e += 256) { const int k = e >> 6, j = e & 63; s_w[7424  + j * 72 + k] = f2bf(wr2[e]); }
    for (int e = tid; e < 192;  e += 256) { const int k = e / 3,  j = e % 3;  s_w[12032 + j * 72 + k] = f2bf(wr3[e]); }
    __syncthreads();

    const int wave = tid >> 6;
    const int lane = tid & 63;
    const int q    = lane >> 4;
    const int mr   = lane & 15;
    unsigned short* hb = s_act + wave * (16 * 72);
    float*          gb = s_geo + wave * (16 * 20);
    const int base = blockIdx.x * 256 + wave * 64;
    if (base >= n) return;

#pragma unroll 1
    for (int mt = 0; mt < 4; ++mt) {
        const int pt = base + mt * 16 + mr;

        short8 aenc;
#pragma unroll
        for (int t = 0; t < 4; ++t) {
            const float2 e = *reinterpret_cast<const float2*>(ws_enc + 2 * ((size_t)(q * 4 + t) * n + pt));
            aenc[2 * t + 0] = (short)f2bf(e.x);
            aenc[2 * t + 1] = (short)f2bf(e.y);
        }

#pragma unroll
        for (int nc = 0; nc < 4; ++nc) {
            const short8 b = *reinterpret_cast<const short8*>(s_w + 0 + (nc * 16 + mr) * 40 + q * 8);
            floatx4 acc = {0.f, 0.f, 0.f, 0.f};
            acc = __builtin_amdgcn_mfma_f32_16x16x32_bf16(aenc, b, acc, 0, 0, 0);
#pragma unroll
            for (int r = 0; r < 4; ++r)
                hb[(q * 4 + r) * 72 + nc * 16 + mr] = f2bf(fmaxf(acc[r], 0.f));
        }
        __builtin_amdgcn_wave_barrier();

        {
            const short8 a0 = *reinterpret_cast<const short8*>(hb + mr * 72 + 0  + q * 8);
            const short8 a1 = *reinterpret_cast<const short8*>(hb + mr * 72 + 32 + q * 8);
            floatx4 acc0 = {0.f, 0.f, 0.f, 0.f};
            floatx4 acc1 = {0.f, 0.f, 0.f, 0.f};
            {
                const short8 b0 = *reinterpret_cast<const short8*>(s_w + 2560 + mr * 72 + 0  + q * 8);
                const short8 b1 = *reinterpret_cast<const short8*>(s_w + 2560 + mr * 72 + 32 + q * 8);
                acc0 = __builtin_amdgcn_mfma_f32_16x16x32_bf16(a0, b0, acc0, 0, 0, 0);
                acc0 = __builtin_amdgcn_mfma_f32_16x16x32_bf16(a1, b1, acc0, 0, 0, 0);
            }
            {
                const short8 b0 = *reinterpret_cast<const short8*>(s_w + 2560 + (16 + mr) * 72 + 0  + q * 8);
                const short8 b1 = *reinterpret_cast<const short8*>(s_w + 2560 + (16 + mr) * 72 + 32 + q * 8);
                acc1 = __builtin_amdgcn_mfma_f32_16x16x32_bf16(a0, b0, acc1, 0, 0, 0);
                acc1 = __builtin_amdgcn_mfma_f32_16x16x32_bf16(a1, b1, acc1, 0, 0, 0);
            }
#pragma unroll
            for (int r = 0; r < 4; ++r) gb[(q * 4 + r) * 20 + mr + 3] = acc0[r];
            if (mr == 0) {
#pragma unroll
                for (int r = 0; r < 4; ++r) gb[(q * 4 + r) * 20 + 19] = acc1[r];
            }
        }
        __builtin_amdgcn_wave_barrier();

        if (lane < 16)
            out[3 * (size_t)n + (size_t)(base + mt * 16 + lane)] = fmaxf(gb[lane * 20 + 3], 0.f);

        const float dx = dirv[3 * (size_t)pt + 0] * 2.0f - 1.0f;
        const float dy = dirv[3 * (size_t)pt + 1] * 2.0f - 1.0f;
        const float dz = dirv[3 * (size_t)pt + 2] * 2.0f - 1.0f;
        const float x2 = dx * dx, y2 = dy * dy, z2 = dz * dz;
        const float xy = dx * dy, yz = dy * dz, xz = dx * dz;
        float sh[16];
        sh[0]  = 0.28209479177387814f;
        sh[1]  = -0.48860251190291987f * dy;
        sh[2]  = 0.48860251190291987f * dz;
        sh[3]  = -0.48860251190291987f * dx;
        sh[4]  = 1.0925484305920792f * xy;
        sh[5]  = -1.0925484305920792f * yz;
        sh[6]  = 0.94617469575756f * z2 - 0.31539156525252f;
        sh[7]  = -1.0925484305920792f * xz;
        sh[8]  = 0.5462742152960396f * (x2 - y2);
        sh[9]  = 0.5900435899266435f * dy * (-3.0f * x2 + y2);
        sh[10] = 2.890611442640554f * xy * dz;
        sh[11] = 0.4570457994644657f * dy * (1.0f - 5.0f * z2);
        sh[12] = 0.3731763325901154f * dz * (5.0f * z2 - 3.0f);
        sh[13] = 0.4570457994644657f * dx * (1.0f - 5.0f * z2);
        sh[14] = 1.445305721320277f * dz * (x2 - y2);
        sh[15] = 0.5900435899266435f * dx * (-x2 + 3.0f * y2);

        short8 ar;
        if (q < 2) {
#pragma unroll
            for (int j = 0; j < 8; ++j) ar[j] = (short)f2bf(sh[q * 8 + j]);
        } else {
            const floatx4 g0 = *reinterpret_cast<const floatx4*>(gb + mr * 20 + 4 + (q - 2) * 8);
            const floatx4 g1 = *reinterpret_cast<const floatx4*>(gb + mr * 20 + 8 + (q - 2) * 8);
#pragma unroll
            for (int j = 0; j < 4; ++j) { ar[j] = (short)f2bf(g0[j]); ar[4 + j] = (short)f2bf(g1[j]); }
        }

#pragma unroll
        for (int nc = 0; nc < 4; ++nc) {
            const short8 b = *reinterpret_cast<const short8*>(s_w + 4864 + (nc * 16 + mr) * 40 + q * 8);
            floatx4 acc = {0.f, 0.f, 0.f, 0.f};
            acc = __builtin_amdgcn_mfma_f32_16x16x32_bf16(ar, b, acc, 0, 0, 0);
#pragma unroll
            for (int r = 0; r < 4; ++r)
                hb[(q * 4 + r) * 72 + nc * 16 + mr] = f2bf(fmaxf(acc[r], 0.f));
        }
        __builtin_amdgcn_wave_barrier();

        {
            const short8 a0 = *reinterpret_cast<const short8*>(hb + mr * 72 + 0  + q * 8);
            const short8 a1 = *reinterpret_cast<const short8*>(hb + mr * 72 + 32 + q * 8);
            __builtin_amdgcn_wave_barrier();
#pragma unroll
            for (int nc = 0; nc < 4; ++nc) {
                const short8 b0 = *reinterpret_cast<const short8*>(s_w + 7424 + (nc * 16 + mr) * 72 + 0  + q * 8);
                const short8 b1 = *reinterpret_cast<const short8*>(s_w + 7424 + (nc * 16 + mr) * 72 + 32 + q * 8);
                floatx4 acc = {0.f, 0.f, 0.f, 0.f};
                acc = __builtin_amdgcn_mfma_f32_16x16x32_bf16(a0, b0, acc, 0, 0, 0);
                acc = __builtin_amdgcn_mfma_f32_16x16x32_bf16(a1, b1, acc, 0, 0, 0);
#pragma unroll
                for (int r = 0; r < 4; ++r)
                    hb[(q * 4 + r) * 72 + nc * 16 + mr] = f2bf(fmaxf(acc[r], 0.f));
            }
        }
        __builtin_amdgcn_wave_barrier();

        {
            const short8 a0 = *reinterpret_cast<const short8*>(hb + mr * 72 + 0  + q * 8);
            const short8 a1 = *reinterpret_cast<const short8*>(hb + mr * 72 + 32 + q * 8);
            const short8 b0 = *reinterpret_cast<const short8*>(s_w + 12032 + mr * 72 + 0  + q * 8);
            const short8 b1 = *reinterpret_cast<const short8*>(s_w + 12032 + mr * 72 + 32 + q * 8);
            floatx4 acc = {0.f, 0.f, 0.f, 0.f};
            acc = __builtin_amdgcn_mfma_f32_16x16x32_bf16(a0, b0, acc, 0, 0, 0);
            acc = __builtin_amdgcn_mfma_f32_16x16x32_bf16(a1, b1, acc, 0, 0, 0);
            if (mr < 3) {
#pragma unroll
                for (int r = 0; r < 4; ++r) {
                    const int p = base + mt * 16 + q * 4 + r;
                    out[3 * (size_t)p + mr] = 1.0f / (1.0f + __expf(-acc[r]));
                }
            }
        }
        __builtin_amdgcn_wave_barrier();
    }
}

// ---------------------------------------------------------------------------
// Fallback: fused kernel (used only if ws can't hold enc or n % 1024 != 0).
// ---------------------------------------------------------------------------
__global__ __launch_bounds__(256, 4)
void nerf_fused(const float* __restrict__ xyz,
                const float* __restrict__ dirv,
                const float* __restrict__ table,
                const float* __restrict__ ws1,
                const float* __restrict__ ws2,
                const float* __restrict__ wr1,
                const float* __restrict__ wr2,
                const float* __restrict__ wr3,
                float* __restrict__ out,
                int n)
{
    constexpr unsigned RES[16] = RES_LIST;

    const int i = blockIdx.x * 256 + threadIdx.x;
    if (i >= n) return;

    const float px_ = xyz[3 * (size_t)i + 0];
    const float py_ = xyz[3 * (size_t)i + 1];
    const float pz_ = xyz[3 * (size_t)i + 2];

    float enc[32];
#pragma unroll
    for (int l = 0; l < 16; ++l) {
        const unsigned res = RES[l];
        const float fr = (float)res;
        const float posx = px_ * fr, posy = py_ * fr, posz = pz_ * fr;
        const float fx = floorf(posx), fy = floorf(posy), fz = floorf(posz);
        const float wx = posx - fx, wy = posy - fy, wz = posz - fz;
        const unsigned x0 = (unsigned)fx, y0 = (unsigned)fy, z0 = (unsigned)fz;
        const float* tb = table + (size_t)l * (TBL * 2);
        float a0 = 0.0f, a1 = 0.0f;
#pragma unroll
        for (int c = 0; c < 8; ++c) {
            const unsigned cx = x0 + (c & 1);
            const unsigned cy = y0 + ((c >> 1) & 1);
            const unsigned cz = z0 + ((c >> 2) & 1);
            unsigned idx;
            if (l < 5) {
                const unsigned s = res + 1u;
                idx = cx + cy * s + cz * (s * s);
            } else {
                idx = (cx * 1u) ^ (cy * 2654435761u) ^ (cz * 805459861u);
                idx &= (unsigned)(TBL - 1);
            }
            const float w = ((c & 1) ? wx : 1.0f - wx) *
                            ((c & 2) ? wy : 1.0f - wy) *
                            ((c & 4) ? wz : 1.0f - wz);
            const float2 f = *reinterpret_cast<const float2*>(tb + 2u * idx);
            a0 = fmaf(f.x, w, a0);
            a1 = fmaf(f.y, w, a1);
        }
        enc[2 * l + 0] = a0;
        enc[2 * l + 1] = a1;
    }

    float h[64];
#pragma unroll
    for (int j = 0; j < 64; ++j) h[j] = 0.0f;
#pragma unroll
    for (int k = 0; k < 32; ++k) {
        const float e = enc[k];
#pragma unroll
        for (int j = 0; j < 64; ++j) h[j] = fmaf(e, ws1[k * 64 + j], h[j]);
    }
#pragma unroll
    for (int j = 0; j < 64; ++j) h[j] = relu_f(h[j]);

    float geo[17];
#pragma unroll
    for (int j = 0; j < 17; ++j) geo[j] = 0.0f;
#pragma unroll
    for (int k = 0; k < 64; ++k) {
        const float e = h[k];
#pragma unroll
        for (int j = 0; j < 17; ++j) geo[j] = fmaf(e, ws2[k * 17 + j], geo[j]);
    }
    out[3 * (size_t)n + (size_t)i] = relu_f(geo[0]);

    const float dx = dirv[3 * (size_t)i + 0] * 2.0f - 1.0f;
    const float dy = dirv[3 * (size_t)i + 1] * 2.0f - 1.0f;
    const float dz = dirv[3 * (size_t)i + 2] * 2.0f - 1.0f;
    const float x2 = dx * dx, y2 = dy * dy, z2 = dz * dz;
    const float xy = dx * dy, yz = dy * dz, xz = dx * dz;

    float sh[16];
    sh[0]  = 0.28209479177387814f;
    sh[1]  = -0.48860251190291987f * dy;
    sh[2]  = 0.48860251190291987f * dz;
    sh[3]  = -0.48860251190291987f * dx;
    sh[4]  = 1.0925484305920792f * xy;
    sh[5]  = -1.0925484305920792f * yz;
    sh[6]  = 0.94617469575756f * z2 - 0.31539156525252f;
    sh[7]  = -1.0925484305920792f * xz;
    sh[8]  = 0.5462742152960396f * (x2 - y2);
    sh[9]  = 0.5900435899266435f * dy * (-3.0f * x2 + y2);
    sh[10] = 2.890611442640554f * xy * dz;
    sh[11] = 0.4570457994644657f * dy * (1.0f - 5.0f * z2);
    sh[12] = 0.3731763325901154f * dz * (5.0f * z2 - 3.0f);
    sh[13] = 0.4570457994644657f * dx * (1.0f - 5.0f * z2);
    sh[14] = 1.445305721320277f * dz * (x2 - y2);
    sh[15] = 0.5900435899266435f * dx * (-x2 + 3.0f * y2);

    float g[64];
#pragma unroll
    for (int j = 0; j < 64; ++j) g[j] = 0.0f;
#pragma unroll
    for (int k = 0; k < 16; ++k) {
        const float e = sh[k];
#pragma unroll
        for (int j = 0; j < 64; ++j) g[j] = fmaf(e, wr1[k * 64 + j], g[j]);
    }
#pragma unroll
    for (int k = 16; k < 32; ++k) {
        const float e = geo[k - 15];
#pragma unroll
        for (int j = 0; j < 64; ++j) g[j] = fmaf(e, wr1[k * 64 + j], g[j]);
    }
#pragma unroll
    for (int j = 0; j < 64; ++j) g[j] = relu_f(g[j]);

    float r0 = 0.0f, r1 = 0.0f, r2 = 0.0f;
#pragma unroll
    for (int half = 0; half < 2; ++half) {
        const int j0 = half * 32;
        float g2h[32];
#pragma unroll
        for (int j = 0; j < 32; ++j) g2h[j] = 0.0f;
#pragma unroll
        for (int k = 0; k < 64; ++k) {
            const float e = g[k];
#pragma unroll
            for (int j = 0; j < 32; ++j) g2h[j] = fmaf(e, wr2[k * 64 + j0 + j], g2h[j]);
        }
#pragma unroll
        for (int j = 0; j < 32; ++j) {
            const float e = relu_f(g2h[j]);
            r0 = fmaf(e, wr3[(j0 + j) * 3 + 0], r0);
            r1 = fmaf(e, wr3[(j0 + j) * 3 + 1], r1);
            r2 = fmaf(e, wr3[(j0 + j) * 3 + 2], r2);
        }
    }

    out[3 * (size_t)i + 0] = 1.0f / (1.0f + __expf(-r0));
    out[3 * (size_t)i + 1] = 1.0f / (1.0f + __expf(-r1));
    out[3 * (size_t)i + 2] = 1.0f / (1.0f + __expf(-r2));
}

extern "C" void kernel_launch(void* const* d_in, const int* in_sizes, int n_in,
                              void* d_out, int out_size, void* d_ws, size_t ws_size,
                              hipStream_t stream)
{
    const float* xyz   = (const float*)d_in[0];
    const float* dirv  = (const float*)d_in[1];
    const float* table = (const float*)d_in[2];
    const float* ws1   = (const float*)d_in[3];
    const float* ws2   = (const float*)d_in[4];
    const float* wr1   = (const float*)d_in[5];
    const float* wr2   = (const float*)d_in[6];
    const float* wr3   = (const float*)d_in[7];
    float* out = (float*)d_out;

    const int n = in_sizes[0] / 3;
    const int blocks_per_level = (n + 255) / 256;
    dim3 block(256);
    dim3 grid_mlp(blocks_per_level);

    const size_t enc_bytes = (size_t)n * 16 * sizeof(float2);   // 268 MB at n=2^21
    if (ws_size >= enc_bytes && n >= 1024 && (n & 1023) == 0) {
        float* ws_enc = (float*)d_ws;
        // 64 quarter-units (16 levels x 4 quarters), 8 sequential units per XCD
        dim3 grid_enc(8u * 8u * (unsigned)(n >> 10));
        hipLaunchKernelGGL(encode_sched, grid_enc, block, 0, stream,
                           xyz, table, ws_enc, n);
        hipLaunchKernelGGL(mlp_mfma, grid_mlp, block, 0, stream,
                           ws_enc, dirv, ws1, ws2, wr1, wr2, wr3, out, n);
    } else {
        hipLaunchKernelGGL(nerf_fused, grid_mlp, block, 0, stream,
                           xyz, dirv, table, ws1, ws2, wr1, wr2, wr3, out, n);
    }
}

// Round 4
// 1014.425 us; speedup vs baseline: 1.0914x; 1.0349x over previous
//
#include <hip/hip_runtime.h>
#include <hip/hip_bf16.h>
#include <cmath>

#define TBL (1 << 19)   // T = 2^19 hash table entries per level (power of two)

__device__ __forceinline__ float relu_f(float x) { return fmaxf(x, 0.0f); }

// fp32 -> bf16 bits, round-to-nearest-even
__device__ __forceinline__ unsigned short f2bf(float x) {
    union { float f; unsigned u; } v; v.f = x;
    const unsigned r = v.u + 0x7FFFu + ((v.u >> 16) & 1u);
    return (unsigned short)(r >> 16);
}

typedef __attribute__((ext_vector_type(8))) short short8;   // 8 bf16 = 4 VGPRs (A/B frag)
typedef __attribute__((ext_vector_type(4))) float floatx4;  // C/D frag

// res_l = floor(16 * 1.3819^l); dense iff (res+1)^3 <= 2^19  (l = 0..4)
#define RES_LIST {16, 22, 30, 42, 58, 80, 111, 153, 212, 294, 406, 561, 775, 1072, 1481, 2047}

// ---------------------------------------------------------------------------
// Single-dispatch scheduled encode. L2-REQUEST-RATE bound (~16 req/cy/XCD):
// 233M line-requests -> 740us measured (round 3). This version cuts requests:
//   - hashed pairing (even x0 -> aligned float4, PRIMES[0]==1): 6 req/pt avg
//   - dense parity pairing: s odd => idx parity alternates; even idx -> one
//     aligned float4 (2 of 4 corner-pairs) -> 6 req/pt guaranteed
//   - enc output packed bf16 (u32/point-level): write requests halve; values
//     entering the MFMA are bit-identical (f2bf moved from MLP to encode).
// Schedule: 8 sequential quarter-units per XCD, hashed levels split across
// two XCDs (L2 residency for the 4MB tables), dense filling the remainder.
// ---------------------------------------------------------------------------
__global__ __launch_bounds__(256, 8)
void encode_sched(const float* __restrict__ xyz,
                  const float* __restrict__ table,
                  unsigned* __restrict__ ws_enc,   // u32 = 2 bf16, [level*n + i]
                  int n)
{
    constexpr unsigned RES[16] = RES_LIST;
    constexpr unsigned LEVP[8] = {0x00665555u, 0x00777766u, 0x11998888u, 0x11AAAA99u,
                                  0x222CBBBBu, 0x332DDCCCu, 0x433EEEDDu, 0x444FFFFEu};
    constexpr unsigned QTRP[8] = {0x44E4u, 0xEE4Eu, 0x44E4u, 0xEE4Eu,
                                  0x90E4u, 0x4D39u, 0x3A4Eu, 0xE793u};

    const int xcd      = (int)(blockIdx.x & 7u);
    const unsigned g   = blockIdx.x >> 3;
    const unsigned upb = (unsigned)(n >> 10);     // blocks per quarter-unit
    const int unit     = (int)(g / upb);
    const int slot     = (int)(g % upb);
    const int level    = (int)((LEVP[xcd] >> (4 * unit)) & 15u);
    const int quarter  = (int)((QTRP[xcd] >> (2 * unit)) & 3u);
    const int i        = quarter * (n >> 2) + slot * 256 + (int)threadIdx.x;
    if (i >= n) return;

    const float px_ = __builtin_nontemporal_load(xyz + 3 * (size_t)i + 0);
    const float py_ = __builtin_nontemporal_load(xyz + 3 * (size_t)i + 1);
    const float pz_ = __builtin_nontemporal_load(xyz + 3 * (size_t)i + 2);

    const unsigned res = RES[level];
    const float fr = (float)res;
    const float posx = px_ * fr, posy = py_ * fr, posz = pz_ * fr;
    const float fx = floorf(posx), fy = floorf(posy), fz = floorf(posz);
    const float wx = posx - fx, wy = posy - fy, wz = posz - fz;
    const unsigned x0 = (unsigned)fx, y0 = (unsigned)fy, z0 = (unsigned)fz;
    const float* tb = table + (size_t)level * (TBL * 2);

    float a0 = 0.0f, a1 = 0.0f;
    const float wx1 = wx, wx0 = 1.0f - wx;

    if (level < 5) {
        const unsigned s = res + 1u;
        const unsigned s2 = s * s;
        const unsigned base = x0 + y0 * s + z0 * s2;
#pragma unroll
        for (int c = 0; c < 4; ++c) {
            const unsigned dy = c & 1, dz = c >> 1;
            const unsigned idx = base + dy * s + dz * s2;
            const float wyz = (dy ? wy : 1.0f - wy) * (dz ? wz : 1.0f - wz);
            const float w0 = wyz * wx0, w1 = wyz * wx1;
            float e0x, e0y, e1x, e1y;
            if (!(idx & 1u)) {
                // even idx: entries idx, idx+1 in one aligned 16B slot
                const float4 f = *reinterpret_cast<const float4*>(tb + 2u * idx);
                e0x = f.x; e0y = f.y; e1x = f.z; e1y = f.w;
            } else {
                const float2 f0 = *reinterpret_cast<const float2*>(tb + 2u * idx);
                const float2 f1 = *reinterpret_cast<const float2*>(tb + 2u * idx + 2u);
                e0x = f0.x; e0y = f0.y; e1x = f1.x; e1y = f1.y;
            }
            a0 = fmaf(e0x, w0, fmaf(e1x, w1, a0));
            a1 = fmaf(e0y, w0, fmaf(e1y, w1, a1));
        }
    } else {
#pragma unroll
        for (int c = 0; c < 4; ++c) {
            const unsigned dy = c & 1, dz = c >> 1;
            const unsigned hh = (y0 + dy) * 2654435761u ^ (z0 + dz) * 805459861u;
            const float wyz = (dy ? wy : 1.0f - wy) * (dz ? wz : 1.0f - wz);
            const float w0 = wyz * wx0, w1 = wyz * wx1;
            const unsigned i0 = (x0 ^ hh) & (unsigned)(TBL - 1);
            if (!(x0 & 1u)) {
                // x0 even: idx(x0+1) = i0^1 -> one aligned 16B slot
                const float4 f = *reinterpret_cast<const float4*>(tb + 2u * (i0 & ~1u));
                const bool hi = (i0 & 1u) != 0u;       // position of the x0 entry
                const float e0x = hi ? f.z : f.x, e0y = hi ? f.w : f.y;
                const float e1x = hi ? f.x : f.z, e1y = hi ? f.y : f.w;
                a0 = fmaf(e0x, w0, fmaf(e1x, w1, a0));
                a1 = fmaf(e0y, w0, fmaf(e1y, w1, a1));
            } else {
                const unsigned i1 = ((x0 + 1u) ^ hh) & (unsigned)(TBL - 1);
                const float2 f0 = *reinterpret_cast<const float2*>(tb + 2u * i0);
                const float2 f1 = *reinterpret_cast<const float2*>(tb + 2u * i1);
                a0 = fmaf(f0.x, w0, fmaf(f1.x, w1, a0));
                a1 = fmaf(f0.y, w0, fmaf(f1.y, w1, a1));
            }
        }
    }

    const unsigned pack = (unsigned)f2bf(a0) | ((unsigned)f2bf(a1) << 16);
    __builtin_nontemporal_store(pack, ws_enc + ((size_t)level * n + i));
}

// ---------------------------------------------------------------------------
// MFMA MLP. Block = 256 thr = 4 waves; wave owns 64 points = 4 M-tiles of 16.
// enc arrives as packed bf16 u32 -> direct bit-copy into A fragments.
// ---------------------------------------------------------------------------
__global__ __launch_bounds__(256)
void mlp_mfma(const unsigned* __restrict__ ws_enc,
              const float* __restrict__ dirv,
              const float* __restrict__ ws1,   // (32,64)
              const float* __restrict__ ws2,   // (64,17)
              const float* __restrict__ wr1,   // (32,64)
              const float* __restrict__ wr2,   // (64,64)
              const float* __restrict__ wr3,   // (64,3)
              float* __restrict__ out,
              int n)
{
    __shared__ alignas(16) unsigned short s_w[13184];
    __shared__ alignas(16) unsigned short s_act[4 * 16 * 72];
    __shared__ alignas(16) float          s_geo[4 * 16 * 20];

    const int tid = threadIdx.x;

    for (int e = tid; e < 13184; e += 256) s_w[e] = 0;
    __syncthreads();
    for (int e = tid; e < 2048; e += 256) { const int k = e >> 6, j = e & 63; s_w[0     + j * 40 + k] = f2bf(ws1[e]); }
    for (int e = tid; e < 1088; e += 256) { const int k = e / 17, j = e % 17; s_w[2560  + j * 72 + k] = f2bf(ws2[e]); }
    for (int e = tid; e < 2048; e += 256) { const int k = e >> 6, j = e & 63; s_w[4864  + j * 40 + k] = f2bf(wr1[e]); }
    for (int e = tid; e < 4096; e += 256) { const int k = e >> 6, j = e & 63; s_w[7424  + j * 72 + k] = f2bf(wr2[e]); }
    for (int e = tid; e < 192;  e += 256) { const int k = e / 3,  j = e % 3;  s_w[12032 + j * 72 + k] = f2bf(wr3[e]); }
    __syncthreads();

    const int wave = tid >> 6;
    const int lane = tid & 63;
    const int q    = lane >> 4;
    const int mr   = lane & 15;
    unsigned short* hb = s_act + wave * (16 * 72);
    float*          gb = s_geo + wave * (16 * 20);
    const int base = blockIdx.x * 256 + wave * 64;
    if (base >= n) return;

#pragma unroll 1
    for (int mt = 0; mt < 4; ++mt) {
        const int pt = base + mt * 16 + mr;

        // ---- enc A-fragment: packed bf16 pair per (level, point)
        short8 aenc;
#pragma unroll
        for (int t = 0; t < 4; ++t) {
            const unsigned e = ws_enc[(size_t)(q * 4 + t) * n + pt];
            aenc[2 * t + 0] = (short)(e & 0xFFFFu);
            aenc[2 * t + 1] = (short)(e >> 16);
        }

#pragma unroll
        for (int nc = 0; nc < 4; ++nc) {
            const short8 b = *reinterpret_cast<const short8*>(s_w + 0 + (nc * 16 + mr) * 40 + q * 8);
            floatx4 acc = {0.f, 0.f, 0.f, 0.f};
            acc = __builtin_amdgcn_mfma_f32_16x16x32_bf16(aenc, b, acc, 0, 0, 0);
#pragma unroll
            for (int r = 0; r < 4; ++r)
                hb[(q * 4 + r) * 72 + nc * 16 + mr] = f2bf(fmaxf(acc[r], 0.f));
        }
        __builtin_amdgcn_wave_barrier();

        {
            const short8 a0 = *reinterpret_cast<const short8*>(hb + mr * 72 + 0  + q * 8);
            const short8 a1 = *reinterpret_cast<const short8*>(hb + mr * 72 + 32 + q * 8);
            floatx4 acc0 = {0.f, 0.f, 0.f, 0.f};
            floatx4 acc1 = {0.f, 0.f, 0.f, 0.f};
            {
                const short8 b0 = *reinterpret_cast<const short8*>(s_w + 2560 + mr * 72 + 0  + q * 8);
                const short8 b1 = *reinterpret_cast<const short8*>(s_w + 2560 + mr * 72 + 32 + q * 8);
                acc0 = __builtin_amdgcn_mfma_f32_16x16x32_bf16(a0, b0, acc0, 0, 0, 0);
                acc0 = __builtin_amdgcn_mfma_f32_16x16x32_bf16(a1, b1, acc0, 0, 0, 0);
            }
            {
                const short8 b0 = *reinterpret_cast<const short8*>(s_w + 2560 + (16 + mr) * 72 + 0  + q * 8);
                const short8 b1 = *reinterpret_cast<const short8*>(s_w + 2560 + (16 + mr) * 72 + 32 + q * 8);
                acc1 = __builtin_amdgcn_mfma_f32_16x16x32_bf16(a0, b0, acc1, 0, 0, 0);
                acc1 = __builtin_amdgcn_mfma_f32_16x16x32_bf16(a1, b1, acc1, 0, 0, 0);
            }
#pragma unroll
            for (int r = 0; r < 4; ++r) gb[(q * 4 + r) * 20 + mr + 3] = acc0[r];
            if (mr == 0) {
#pragma unroll
                for (int r = 0; r < 4; ++r) gb[(q * 4 + r) * 20 + 19] = acc1[r];
            }
        }
        __builtin_amdgcn_wave_barrier();

        if (lane < 16)
            out[3 * (size_t)n + (size_t)(base + mt * 16 + lane)] = fmaxf(gb[lane * 20 + 3], 0.f);

        const float dx = dirv[3 * (size_t)pt + 0] * 2.0f - 1.0f;
        const float dy = dirv[3 * (size_t)pt + 1] * 2.0f - 1.0f;
        const float dz = dirv[3 * (size_t)pt + 2] * 2.0f - 1.0f;
        const float x2 = dx * dx, y2 = dy * dy, z2 = dz * dz;
        const float xy = dx * dy, yz = dy * dz, xz = dx * dz;
        float sh[16];
        sh[0]  = 0.28209479177387814f;
        sh[1]  = -0.48860251190291987f * dy;
        sh[2]  = 0.48860251190291987f * dz;
        sh[3]  = -0.48860251190291987f * dx;
        sh[4]  = 1.0925484305920792f * xy;
        sh[5]  = -1.0925484305920792f * yz;
        sh[6]  = 0.94617469575756f * z2 - 0.31539156525252f;
        sh[7]  = -1.0925484305920792f * xz;
        sh[8]  = 0.5462742152960396f * (x2 - y2);
        sh[9]  = 0.5900435899266435f * dy * (-3.0f * x2 + y2);
        sh[10] = 2.890611442640554f * xy * dz;
        sh[11] = 0.4570457994644657f * dy * (1.0f - 5.0f * z2);
        sh[12] = 0.3731763325901154f * dz * (5.0f * z2 - 3.0f);
        sh[13] = 0.4570457994644657f * dx * (1.0f - 5.0f * z2);
        sh[14] = 1.445305721320277f * dz * (x2 - y2);
        sh[15] = 0.5900435899266435f * dx * (-x2 + 3.0f * y2);

        short8 ar;
        if (q < 2) {
#pragma unroll
            for (int j = 0; j < 8; ++j) ar[j] = (short)f2bf(sh[q * 8 + j]);
        } else {
            const floatx4 g0 = *reinterpret_cast<const floatx4*>(gb + mr * 20 + 4 + (q - 2) * 8);
            const floatx4 g1 = *reinterpret_cast<const floatx4*>(gb + mr * 20 + 8 + (q - 2) * 8);
#pragma unroll
            for (int j = 0; j < 4; ++j) { ar[j] = (short)f2bf(g0[j]); ar[4 + j] = (short)f2bf(g1[j]); }
        }

#pragma unroll
        for (int nc = 0; nc < 4; ++nc) {
            const short8 b = *reinterpret_cast<const short8*>(s_w + 4864 + (nc * 16 + mr) * 40 + q * 8);
            floatx4 acc = {0.f, 0.f, 0.f, 0.f};
            acc = __builtin_amdgcn_mfma_f32_16x16x32_bf16(ar, b, acc, 0, 0, 0);
#pragma unroll
            for (int r = 0; r < 4; ++r)
                hb[(q * 4 + r) * 72 + nc * 16 + mr] = f2bf(fmaxf(acc[r], 0.f));
        }
        __builtin_amdgcn_wave_barrier();

        {
            const short8 a0 = *reinterpret_cast<const short8*>(hb + mr * 72 + 0  + q * 8);
            const short8 a1 = *reinterpret_cast<const short8*>(hb + mr * 72 + 32 + q * 8);
            __builtin_amdgcn_wave_barrier();
#pragma unroll
            for (int nc = 0; nc < 4; ++nc) {
                const short8 b0 = *reinterpret_cast<const short8*>(s_w + 7424 + (nc * 16 + mr) * 72 + 0  + q * 8);
                const short8 b1 = *reinterpret_cast<const short8*>(s_w + 7424 + (nc * 16 + mr) * 72 + 32 + q * 8);
                floatx4 acc = {0.f, 0.f, 0.f, 0.f};
                acc = __builtin_amdgcn_mfma_f32_16x16x32_bf16(a0, b0, acc, 0, 0, 0);
                acc = __builtin_amdgcn_mfma_f32_16x16x32_bf16(a1, b1, acc, 0, 0, 0);
#pragma unroll
                for (int r = 0; r < 4; ++r)
                    hb[(q * 4 + r) * 72 + nc * 16 + mr] = f2bf(fmaxf(acc[r], 0.f));
            }
        }
        __builtin_amdgcn_wave_barrier();

        {
            const short8 a0 = *reinterpret_cast<const short8*>(hb + mr * 72 + 0  + q * 8);
            const short8 a1 = *reinterpret_cast<const short8*>(hb + mr * 72 + 32 + q * 8);
            const short8 b0 = *reinterpret_cast<const short8*>(s_w + 12032 + mr * 72 + 0  + q * 8);
            const short8 b1 = *reinterpret_cast<const short8*>(s_w + 12032 + mr * 72 + 32 + q * 8);
            floatx4 acc = {0.f, 0.f, 0.f, 0.f};
            acc = __builtin_amdgcn_mfma_f32_16x16x32_bf16(a0, b0, acc, 0, 0, 0);
            acc = __builtin_amdgcn_mfma_f32_16x16x32_bf16(a1, b1, acc, 0, 0, 0);
            if (mr < 3) {
#pragma unroll
                for (int r = 0; r < 4; ++r) {
                    const int p = base + mt * 16 + q * 4 + r;
                    out[3 * (size_t)p + mr] = 1.0f / (1.0f + __expf(-acc[r]));
                }
            }
        }
        __builtin_amdgcn_wave_barrier();
    }
}

// ---------------------------------------------------------------------------
// Fallback: fused kernel (used only if ws can't hold enc or n % 1024 != 0).
// ---------------------------------------------------------------------------
__global__ __launch_bounds__(256, 4)
void nerf_fused(const float* __restrict__ xyz,
                const float* __restrict__ dirv,
                const float* __restrict__ table,
                const float* __restrict__ ws1,
                const float* __restrict__ ws2,
                const float* __restrict__ wr1,
                const float* __restrict__ wr2,
                const float* __restrict__ wr3,
                float* __restrict__ out,
                int n)
{
    constexpr unsigned RES[16] = RES_LIST;

    const int i = blockIdx.x * 256 + threadIdx.x;
    if (i >= n) return;

    const float px_ = xyz[3 * (size_t)i + 0];
    const float py_ = xyz[3 * (size_t)i + 1];
    const float pz_ = xyz[3 * (size_t)i + 2];

    float enc[32];
#pragma unroll
    for (int l = 0; l < 16; ++l) {
        const unsigned res = RES[l];
        const float fr = (float)res;
        const float posx = px_ * fr, posy = py_ * fr, posz = pz_ * fr;
        const float fx = floorf(posx), fy = floorf(posy), fz = floorf(posz);
        const float wx = posx - fx, wy = posy - fy, wz = posz - fz;
        const unsigned x0 = (unsigned)fx, y0 = (unsigned)fy, z0 = (unsigned)fz;
        const float* tb = table + (size_t)l * (TBL * 2);
        float a0 = 0.0f, a1 = 0.0f;
#pragma unroll
        for (int c = 0; c < 8; ++c) {
            const unsigned cx = x0 + (c & 1);
            const unsigned cy = y0 + ((c >> 1) & 1);
            const unsigned cz = z0 + ((c >> 2) & 1);
            unsigned idx;
            if (l < 5) {
                const unsigned s = res + 1u;
                idx = cx + cy * s + cz * (s * s);
            } else {
                idx = (cx * 1u) ^ (cy * 2654435761u) ^ (cz * 805459861u);
                idx &= (unsigned)(TBL - 1);
            }
            const float w = ((c & 1) ? wx : 1.0f - wx) *
                            ((c & 2) ? wy : 1.0f - wy) *
                            ((c & 4) ? wz : 1.0f - wz);
            const float2 f = *reinterpret_cast<const float2*>(tb + 2u * idx);
            a0 = fmaf(f.x, w, a0);
            a1 = fmaf(f.y, w, a1);
        }
        enc[2 * l + 0] = a0;
        enc[2 * l + 1] = a1;
    }

    float h[64];
#pragma unroll
    for (int j = 0; j < 64; ++j) h[j] = 0.0f;
#pragma unroll
    for (int k = 0; k < 32; ++k) {
        const float e = enc[k];
#pragma unroll
        for (int j = 0; j < 64; ++j) h[j] = fmaf(e, ws1[k * 64 + j], h[j]);
    }
#pragma unroll
    for (int j = 0; j < 64; ++j) h[j] = relu_f(h[j]);

    float geo[17];
#pragma unroll
    for (int j = 0; j < 17; ++j) geo[j] = 0.0f;
#pragma unroll
    for (int k = 0; k < 64; ++k) {
        const float e = h[k];
#pragma unroll
        for (int j = 0; j < 17; ++j) geo[j] = fmaf(e, ws2[k * 17 + j], geo[j]);
    }
    out[3 * (size_t)n + (size_t)i] = relu_f(geo[0]);

    const float dx = dirv[3 * (size_t)i + 0] * 2.0f - 1.0f;
    const float dy = dirv[3 * (size_t)i + 1] * 2.0f - 1.0f;
    const float dz = dirv[3 * (size_t)i + 2] * 2.0f - 1.0f;
    const float x2 = dx * dx, y2 = dy * dy, z2 = dz * dz;
    const float xy = dx * dy, yz = dy * dz, xz = dx * dz;

    float sh[16];
    sh[0]  = 0.28209479177387814f;
    sh[1]  = -0.48860251190291987f * dy;
    sh[2]  = 0.48860251190291987f * dz;
    sh[3]  = -0.48860251190291987f * dx;
    sh[4]  = 1.0925484305920792f * xy;
    sh[5]  = -1.0925484305920792f * yz;
    sh[6]  = 0.94617469575756f * z2 - 0.31539156525252f;
    sh[7]  = -1.0925484305920792f * xz;
    sh[8]  = 0.5462742152960396f * (x2 - y2);
    sh[9]  = 0.5900435899266435f * dy * (-3.0f * x2 + y2);
    sh[10] = 2.890611442640554f * xy * dz;
    sh[11] = 0.4570457994644657f * dy * (1.0f - 5.0f * z2);
    sh[12] = 0.3731763325901154f * dz * (5.0f * z2 - 3.0f);
    sh[13] = 0.4570457994644657f * dx * (1.0f - 5.0f * z2);
    sh[14] = 1.445305721320277f * dz * (x2 - y2);
    sh[15] = 0.5900435899266435f * dx * (-x2 + 3.0f * y2);

    float g[64];
#pragma unroll
    for (int j = 0; j < 64; ++j) g[j] = 0.0f;
#pragma unroll
    for (int k = 0; k < 16; ++k) {
        const float e = sh[k];
#pragma unroll
        for (int j = 0; j < 64; ++j) g[j] = fmaf(e, wr1[k * 64 + j], g[j]);
    }
#pragma unroll
    for (int k = 16; k < 32; ++k) {
        const float e = geo[k - 15];
#pragma unroll
        for (int j = 0; j < 64; ++j) g[j] = fmaf(e, wr1[k * 64 + j], g[j]);
    }
#pragma unroll
    for (int j = 0; j < 64; ++j) g[j] = relu_f(g[j]);

    float r0 = 0.0f, r1 = 0.0f, r2 = 0.0f;
#pragma unroll
    for (int half = 0; half < 2; ++half) {
        const int j0 = half * 32;
        float g2h[32];
#pragma unroll
        for (int j = 0; j < 32; ++j) g2h[j] = 0.0f;
#pragma unroll
        for (int k = 0; k < 64; ++k) {
            const float e = g[k];
#pragma unroll
            for (int j = 0; j < 32; ++j) g2h[j] = fmaf(e, wr2[k * 64 + j0 + j], g2h[j]);
        }
#pragma unroll
        for (int j = 0; j < 32; ++j) {
            const float e = relu_f(g2h[j]);
            r0 = fmaf(e, wr3[(j0 + j) * 3 + 0], r0);
            r1 = fmaf(e, wr3[(j0 + j) * 3 + 1], r1);
            r2 = fmaf(e, wr3[(j0 + j) * 3 + 2], r2);
        }
    }

    out[3 * (size_t)i + 0] = 1.0f / (1.0f + __expf(-r0));
    out[3 * (size_t)i + 1] = 1.0f / (1.0f + __expf(-r1));
    out[3 * (size_t)i + 2] = 1.0f / (1.0f + __expf(-r2));
}

extern "C" void kernel_launch(void* const* d_in, const int* in_sizes, int n_in,
                              void* d_out, int out_size, void* d_ws, size_t ws_size,
                              hipStream_t stream)
{
    const float* xyz   = (const float*)d_in[0];
    const float* dirv  = (const float*)d_in[1];
    const float* table = (const float*)d_in[2];
    const float* ws1   = (const float*)d_in[3];
    const float* ws2   = (const float*)d_in[4];
    const float* wr1   = (const float*)d_in[5];
    const float* wr2   = (const float*)d_in[6];
    const float* wr3   = (const float*)d_in[7];
    float* out = (float*)d_out;

    const int n = in_sizes[0] / 3;
    const int blocks_per_level = (n + 255) / 256;
    dim3 block(256);
    dim3 grid_mlp(blocks_per_level);

    const size_t enc_bytes = (size_t)n * 16 * sizeof(unsigned);   // 134 MB at n=2^21
    if (ws_size >= enc_bytes && n >= 1024 && (n & 1023) == 0) {
        unsigned* ws_enc = (unsigned*)d_ws;
        // 64 quarter-units (16 levels x 4 quarters), 8 sequential units per XCD
        dim3 grid_enc(8u * 8u * (unsigned)(n >> 10));
        hipLaunchKernelGGL(encode_sched, grid_enc, block, 0, stream,
                           xyz, table, ws_enc, n);
        hipLaunchKernelGGL(mlp_mfma, grid_mlp, block, 0, stream,
                           ws_enc, dirv, ws1, ws2, wr1, wr2, wr3, out, n);
    } else {
        hipLaunchKernelGGL(nerf_fused, grid_mlp, block, 0, stream,
                           xyz, dirv, table, ws1, ws2, wr1, wr2, wr3, out, n);
    }
}

// Round 5
// 982.220 us; speedup vs baseline: 1.1272x; 1.0328x over previous
//
#include <hip/hip_runtime.h>
#include <hip/hip_bf16.h>
#include <cmath>

#define TBL (1 << 19)   // T = 2^19 hash table entries per level (power of two)

__device__ __forceinline__ float relu_f(float x) { return fmaxf(x, 0.0f); }

// fp32 -> bf16 bits, round-to-nearest-even
__device__ __forceinline__ unsigned short f2bf(float x) {
    union { float f; unsigned u; } v; v.f = x;
    const unsigned r = v.u + 0x7FFFu + ((v.u >> 16) & 1u);
    return (unsigned short)(r >> 16);
}

typedef __attribute__((ext_vector_type(8))) short short8;   // 8 bf16 = 4 VGPRs (A/B frag)
typedef __attribute__((ext_vector_type(4))) float floatx4;  // C/D frag

// res_l = floor(16 * 1.3819^l); dense iff (res+1)^3 <= 2^19  (l = 0..4)
#define RES_LIST {16, 22, 30, 42, 58, 80, 111, 153, 212, 294, 406, 561, 775, 1072, 1481, 2047}

// ---------------------------------------------------------------------------
// Symmetric scheduled encode. L2-request-rate bound (~16 req/cy/XCD).
// Round-4 lesson: per-XCD request load was imbalanced (18.6-24.5 Mreq) because
// dense levels 2-4 cost nearly as much as hashed. Fix: every XCD processes its
// OWN EIGHTH of the points for EVERY level, sequentially -> identical work mix
// on all XCDs -> perfect balance under any cost model. Level order interleaves
// small dense tables between 4MB hashed tables to soften L2 phase boundaries.
// Request cuts kept from round 4: hashed even-x0 float4 pairing (PRIMES[0]==1
// => idx(x0+1)=idx(x0)^1), dense parity pairing, packed-bf16 output.
// ---------------------------------------------------------------------------
__global__ __launch_bounds__(256, 8)
void encode_sched(const float* __restrict__ xyz,
                  const float* __restrict__ table,
                  unsigned* __restrict__ ws_enc,   // u32 = 2 bf16, [level*n + i]
                  int n)
{
    constexpr unsigned RES[16] = RES_LIST;
    constexpr int LEVORD[16] = {5, 0, 6, 1, 7, 2, 8, 3, 9, 4, 10, 11, 12, 13, 14, 15};

    const int xcd      = (int)(blockIdx.x & 7u);
    const unsigned g   = blockIdx.x >> 3;
    const unsigned upb = (unsigned)(n >> 11);     // blocks per (xcd, level) phase
    const int unit     = (int)(g / upb);
    const int slot     = (int)(g % upb);
    const int level    = LEVORD[unit & 15];
    const int i        = xcd * (n >> 3) + slot * 256 + (int)threadIdx.x;
    if (i >= n) return;

    const float px_ = __builtin_nontemporal_load(xyz + 3 * (size_t)i + 0);
    const float py_ = __builtin_nontemporal_load(xyz + 3 * (size_t)i + 1);
    const float pz_ = __builtin_nontemporal_load(xyz + 3 * (size_t)i + 2);

    const unsigned res = RES[level];
    const float fr = (float)res;
    const float posx = px_ * fr, posy = py_ * fr, posz = pz_ * fr;
    const float fx = floorf(posx), fy = floorf(posy), fz = floorf(posz);
    const float wx = posx - fx, wy = posy - fy, wz = posz - fz;
    const unsigned x0 = (unsigned)fx, y0 = (unsigned)fy, z0 = (unsigned)fz;
    const float* tb = table + (size_t)level * (TBL * 2);

    float a0 = 0.0f, a1 = 0.0f;
    const float wx1 = wx, wx0 = 1.0f - wx;

    if (level < 5) {
        const unsigned s = res + 1u;
        const unsigned s2 = s * s;
        const unsigned base = x0 + y0 * s + z0 * s2;
#pragma unroll
        for (int c = 0; c < 4; ++c) {
            const unsigned dy = c & 1, dz = c >> 1;
            const unsigned idx = base + dy * s + dz * s2;
            const float wyz = (dy ? wy : 1.0f - wy) * (dz ? wz : 1.0f - wz);
            const float w0 = wyz * wx0, w1 = wyz * wx1;
            float e0x, e0y, e1x, e1y;
            if (!(idx & 1u)) {
                // even idx: entries idx, idx+1 in one aligned 16B slot
                const float4 f = *reinterpret_cast<const float4*>(tb + 2u * idx);
                e0x = f.x; e0y = f.y; e1x = f.z; e1y = f.w;
            } else {
                const float2 f0 = *reinterpret_cast<const float2*>(tb + 2u * idx);
                const float2 f1 = *reinterpret_cast<const float2*>(tb + 2u * idx + 2u);
                e0x = f0.x; e0y = f0.y; e1x = f1.x; e1y = f1.y;
            }
            a0 = fmaf(e0x, w0, fmaf(e1x, w1, a0));
            a1 = fmaf(e0y, w0, fmaf(e1y, w1, a1));
        }
    } else {
#pragma unroll
        for (int c = 0; c < 4; ++c) {
            const unsigned dy = c & 1, dz = c >> 1;
            const unsigned hh = (y0 + dy) * 2654435761u ^ (z0 + dz) * 805459861u;
            const float wyz = (dy ? wy : 1.0f - wy) * (dz ? wz : 1.0f - wz);
            const float w0 = wyz * wx0, w1 = wyz * wx1;
            const unsigned i0 = (x0 ^ hh) & (unsigned)(TBL - 1);
            if (!(x0 & 1u)) {
                // x0 even: idx(x0+1) = i0^1 -> one aligned 16B slot
                const float4 f = *reinterpret_cast<const float4*>(tb + 2u * (i0 & ~1u));
                const bool hi = (i0 & 1u) != 0u;       // position of the x0 entry
                const float e0x = hi ? f.z : f.x, e0y = hi ? f.w : f.y;
                const float e1x = hi ? f.x : f.z, e1y = hi ? f.y : f.w;
                a0 = fmaf(e0x, w0, fmaf(e1x, w1, a0));
                a1 = fmaf(e0y, w0, fmaf(e1y, w1, a1));
            } else {
                const unsigned i1 = ((x0 + 1u) ^ hh) & (unsigned)(TBL - 1);
                const float2 f0 = *reinterpret_cast<const float2*>(tb + 2u * i0);
                const float2 f1 = *reinterpret_cast<const float2*>(tb + 2u * i1);
                a0 = fmaf(f0.x, w0, fmaf(f1.x, w1, a0));
                a1 = fmaf(f0.y, w0, fmaf(f1.y, w1, a1));
            }
        }
    }

    const unsigned pack = (unsigned)f2bf(a0) | ((unsigned)f2bf(a1) << 16);
    __builtin_nontemporal_store(pack, ws_enc + ((size_t)level * n + i));
}

// ---------------------------------------------------------------------------
// MFMA MLP. Block = 256 thr = 4 waves; wave owns 64 points = 4 M-tiles of 16.
// Round-4 lesson: latency-bound, not BW-bound (halving input traffic saved
// ~3%). Fix: depth-1 software pipeline — next mt's enc (4 u32) and dirv
// (3 f32) loads issue at iteration top into named registers, hiding global
// latency under the MFMA/LDS chain. launch_bounds(256,2) caps VGPR at 128.
// ---------------------------------------------------------------------------
__global__ __launch_bounds__(256, 2)
void mlp_mfma(const unsigned* __restrict__ ws_enc,
              const float* __restrict__ dirv,
              const float* __restrict__ ws1,   // (32,64)
              const float* __restrict__ ws2,   // (64,17)
              const float* __restrict__ wr1,   // (32,64)
              const float* __restrict__ wr2,   // (64,64)
              const float* __restrict__ wr3,   // (64,3)
              float* __restrict__ out,
              int n)
{
    __shared__ alignas(16) unsigned short s_w[13184];
    __shared__ alignas(16) unsigned short s_act[4 * 16 * 72];
    __shared__ alignas(16) float          s_geo[4 * 16 * 20];

    const int tid = threadIdx.x;

    for (int e = tid; e < 13184; e += 256) s_w[e] = 0;
    __syncthreads();
    for (int e = tid; e < 2048; e += 256) { const int k = e >> 6, j = e & 63; s_w[0     + j * 40 + k] = f2bf(ws1[e]); }
    for (int e = tid; e < 1088; e += 256) { const int k = e / 17, j = e % 17; s_w[2560  + j * 72 + k] = f2bf(ws2[e]); }
    for (int e = tid; e < 2048; e += 256) { const int k = e >> 6, j = e & 63; s_w[4864  + j * 40 + k] = f2bf(wr1[e]); }
    for (int e = tid; e < 4096; e += 256) { const int k = e >> 6, j = e & 63; s_w[7424  + j * 72 + k] = f2bf(wr2[e]); }
    for (int e = tid; e < 192;  e += 256) { const int k = e / 3,  j = e % 3;  s_w[12032 + j * 72 + k] = f2bf(wr3[e]); }
    __syncthreads();

    const int wave = tid >> 6;
    const int lane = tid & 63;
    const int q    = lane >> 4;
    const int mr   = lane & 15;
    unsigned short* hb = s_act + wave * (16 * 72);
    float*          gb = s_geo + wave * (16 * 20);
    const int base = blockIdx.x * 256 + wave * 64;
    if (base >= n) return;

    const int pt0 = base + mr;
    // prime mt=0 prefetch
    unsigned e0 = ws_enc[(size_t)(q * 4 + 0) * n + pt0];
    unsigned e1 = ws_enc[(size_t)(q * 4 + 1) * n + pt0];
    unsigned e2 = ws_enc[(size_t)(q * 4 + 2) * n + pt0];
    unsigned e3 = ws_enc[(size_t)(q * 4 + 3) * n + pt0];
    float dv0 = dirv[3 * (size_t)pt0 + 0];
    float dv1 = dirv[3 * (size_t)pt0 + 1];
    float dv2 = dirv[3 * (size_t)pt0 + 2];

#pragma unroll 1
    for (int mt = 0; mt < 4; ++mt) {
        // ---- issue next-mt global loads early (hidden under compute below)
        unsigned f0 = 0, f1 = 0, f2 = 0, f3 = 0;
        float c0 = 0.f, c1 = 0.f, c2 = 0.f;
        if (mt < 3) {
            const int ptn = pt0 + (mt + 1) * 16;
            f0 = ws_enc[(size_t)(q * 4 + 0) * n + ptn];
            f1 = ws_enc[(size_t)(q * 4 + 1) * n + ptn];
            f2 = ws_enc[(size_t)(q * 4 + 2) * n + ptn];
            f3 = ws_enc[(size_t)(q * 4 + 3) * n + ptn];
            c0 = dirv[3 * (size_t)ptn + 0];
            c1 = dirv[3 * (size_t)ptn + 1];
            c2 = dirv[3 * (size_t)ptn + 2];
        }

        // ---- enc A-fragment from prefetched registers
        short8 aenc;
        aenc[0] = (short)(e0 & 0xFFFFu); aenc[1] = (short)(e0 >> 16);
        aenc[2] = (short)(e1 & 0xFFFFu); aenc[3] = (short)(e1 >> 16);
        aenc[4] = (short)(e2 & 0xFFFFu); aenc[5] = (short)(e2 >> 16);
        aenc[6] = (short)(e3 & 0xFFFFu); aenc[7] = (short)(e3 >> 16);

#pragma unroll
        for (int nc = 0; nc < 4; ++nc) {
            const short8 b = *reinterpret_cast<const short8*>(s_w + 0 + (nc * 16 + mr) * 40 + q * 8);
            floatx4 acc = {0.f, 0.f, 0.f, 0.f};
            acc = __builtin_amdgcn_mfma_f32_16x16x32_bf16(aenc, b, acc, 0, 0, 0);
#pragma unroll
            for (int r = 0; r < 4; ++r)
                hb[(q * 4 + r) * 72 + nc * 16 + mr] = f2bf(fmaxf(acc[r], 0.f));
        }
        __builtin_amdgcn_wave_barrier();

        {
            const short8 a0 = *reinterpret_cast<const short8*>(hb + mr * 72 + 0  + q * 8);
            const short8 a1 = *reinterpret_cast<const short8*>(hb + mr * 72 + 32 + q * 8);
            floatx4 acc0 = {0.f, 0.f, 0.f, 0.f};
            floatx4 acc1 = {0.f, 0.f, 0.f, 0.f};
            {
                const short8 b0 = *reinterpret_cast<const short8*>(s_w + 2560 + mr * 72 + 0  + q * 8);
                const short8 b1 = *reinterpret_cast<const short8*>(s_w + 2560 + mr * 72 + 32 + q * 8);
                acc0 = __builtin_amdgcn_mfma_f32_16x16x32_bf16(a0, b0, acc0, 0, 0, 0);
                acc0 = __builtin_amdgcn_mfma_f32_16x16x32_bf16(a1, b1, acc0, 0, 0, 0);
            }
            {
                const short8 b0 = *reinterpret_cast<const short8*>(s_w + 2560 + (16 + mr) * 72 + 0  + q * 8);
                const short8 b1 = *reinterpret_cast<const short8*>(s_w + 2560 + (16 + mr) * 72 + 32 + q * 8);
                acc1 = __builtin_amdgcn_mfma_f32_16x16x32_bf16(a0, b0, acc1, 0, 0, 0);
                acc1 = __builtin_amdgcn_mfma_f32_16x16x32_bf16(a1, b1, acc1, 0, 0, 0);
            }
#pragma unroll
            for (int r = 0; r < 4; ++r) gb[(q * 4 + r) * 20 + mr + 3] = acc0[r];
            if (mr == 0) {
#pragma unroll
                for (int r = 0; r < 4; ++r) gb[(q * 4 + r) * 20 + 19] = acc1[r];
            }
        }
        __builtin_amdgcn_wave_barrier();

        if (lane < 16)
            out[3 * (size_t)n + (size_t)(base + mt * 16 + lane)] = fmaxf(gb[lane * 20 + 3], 0.f);

        // ---- SH deg-4 from prefetched dirv
        const float dx = dv0 * 2.0f - 1.0f;
        const float dy = dv1 * 2.0f - 1.0f;
        const float dz = dv2 * 2.0f - 1.0f;
        const float x2 = dx * dx, y2 = dy * dy, z2 = dz * dz;
        const float xy = dx * dy, yz = dy * dz, xz = dx * dz;
        float sh[16];
        sh[0]  = 0.28209479177387814f;
        sh[1]  = -0.48860251190291987f * dy;
        sh[2]  = 0.48860251190291987f * dz;
        sh[3]  = -0.48860251190291987f * dx;
        sh[4]  = 1.0925484305920792f * xy;
        sh[5]  = -1.0925484305920792f * yz;
        sh[6]  = 0.94617469575756f * z2 - 0.31539156525252f;
        sh[7]  = -1.0925484305920792f * xz;
        sh[8]  = 0.5462742152960396f * (x2 - y2);
        sh[9]  = 0.5900435899266435f * dy * (-3.0f * x2 + y2);
        sh[10] = 2.890611442640554f * xy * dz;
        sh[11] = 0.4570457994644657f * dy * (1.0f - 5.0f * z2);
        sh[12] = 0.3731763325901154f * dz * (5.0f * z2 - 3.0f);
        sh[13] = 0.4570457994644657f * dx * (1.0f - 5.0f * z2);
        sh[14] = 1.445305721320277f * dz * (x2 - y2);
        sh[15] = 0.5900435899266435f * dx * (-x2 + 3.0f * y2);

        short8 ar;
        if (q < 2) {
#pragma unroll
            for (int j = 0; j < 8; ++j) ar[j] = (short)f2bf(sh[q * 8 + j]);
        } else {
            const floatx4 g0 = *reinterpret_cast<const floatx4*>(gb + mr * 20 + 4 + (q - 2) * 8);
            const floatx4 g1 = *reinterpret_cast<const floatx4*>(gb + mr * 20 + 8 + (q - 2) * 8);
#pragma unroll
            for (int j = 0; j < 4; ++j) { ar[j] = (short)f2bf(g0[j]); ar[4 + j] = (short)f2bf(g1[j]); }
        }

#pragma unroll
        for (int nc = 0; nc < 4; ++nc) {
            const short8 b = *reinterpret_cast<const short8*>(s_w + 4864 + (nc * 16 + mr) * 40 + q * 8);
            floatx4 acc = {0.f, 0.f, 0.f, 0.f};
            acc = __builtin_amdgcn_mfma_f32_16x16x32_bf16(ar, b, acc, 0, 0, 0);
#pragma unroll
            for (int r = 0; r < 4; ++r)
                hb[(q * 4 + r) * 72 + nc * 16 + mr] = f2bf(fmaxf(acc[r], 0.f));
        }
        __builtin_amdgcn_wave_barrier();

        {
            const short8 a0 = *reinterpret_cast<const short8*>(hb + mr * 72 + 0  + q * 8);
            const short8 a1 = *reinterpret_cast<const short8*>(hb + mr * 72 + 32 + q * 8);
            __builtin_amdgcn_wave_barrier();
#pragma unroll
            for (int nc = 0; nc < 4; ++nc) {
                const short8 b0 = *reinterpret_cast<const short8*>(s_w + 7424 + (nc * 16 + mr) * 72 + 0  + q * 8);
                const short8 b1 = *reinterpret_cast<const short8*>(s_w + 7424 + (nc * 16 + mr) * 72 + 32 + q * 8);
                floatx4 acc = {0.f, 0.f, 0.f, 0.f};
                acc = __builtin_amdgcn_mfma_f32_16x16x32_bf16(a0, b0, acc, 0, 0, 0);
                acc = __builtin_amdgcn_mfma_f32_16x16x32_bf16(a1, b1, acc, 0, 0, 0);
#pragma unroll
                for (int r = 0; r < 4; ++r)
                    hb[(q * 4 + r) * 72 + nc * 16 + mr] = f2bf(fmaxf(acc[r], 0.f));
            }
        }
        __builtin_amdgcn_wave_barrier();

        {
            const short8 a0 = *reinterpret_cast<const short8*>(hb + mr * 72 + 0  + q * 8);
            const short8 a1 = *reinterpret_cast<const short8*>(hb + mr * 72 + 32 + q * 8);
            const short8 b0 = *reinterpret_cast<const short8*>(s_w + 12032 + mr * 72 + 0  + q * 8);
            const short8 b1 = *reinterpret_cast<const short8*>(s_w + 12032 + mr * 72 + 32 + q * 8);
            floatx4 acc = {0.f, 0.f, 0.f, 0.f};
            acc = __builtin_amdgcn_mfma_f32_16x16x32_bf16(a0, b0, acc, 0, 0, 0);
            acc = __builtin_amdgcn_mfma_f32_16x16x32_bf16(a1, b1, acc, 0, 0, 0);
            if (mr < 3) {
#pragma unroll
                for (int r = 0; r < 4; ++r) {
                    const int p = base + mt * 16 + q * 4 + r;
                    out[3 * (size_t)p + mr] = 1.0f / (1.0f + __expf(-acc[r]));
                }
            }
        }
        __builtin_amdgcn_wave_barrier();

        e0 = f0; e1 = f1; e2 = f2; e3 = f3;
        dv0 = c0; dv1 = c1; dv2 = c2;
    }
}

// ---------------------------------------------------------------------------
// Fallback: fused kernel (used only if ws can't hold enc or n % 2048 != 0).
// ---------------------------------------------------------------------------
__global__ __launch_bounds__(256, 4)
void nerf_fused(const float* __restrict__ xyz,
                const float* __restrict__ dirv,
                const float* __restrict__ table,
                const float* __restrict__ ws1,
                const float* __restrict__ ws2,
                const float* __restrict__ wr1,
                const float* __restrict__ wr2,
                const float* __restrict__ wr3,
                float* __restrict__ out,
                int n)
{
    constexpr unsigned RES[16] = RES_LIST;

    const int i = blockIdx.x * 256 + threadIdx.x;
    if (i >= n) return;

    const float px_ = xyz[3 * (size_t)i + 0];
    const float py_ = xyz[3 * (size_t)i + 1];
    const float pz_ = xyz[3 * (size_t)i + 2];

    float enc[32];
#pragma unroll
    for (int l = 0; l < 16; ++l) {
        const unsigned res = RES[l];
        const float fr = (float)res;
        const float posx = px_ * fr, posy = py_ * fr, posz = pz_ * fr;
        const float fx = floorf(posx), fy = floorf(posy), fz = floorf(posz);
        const float wx = posx - fx, wy = posy - fy, wz = posz - fz;
        const unsigned x0 = (unsigned)fx, y0 = (unsigned)fy, z0 = (unsigned)fz;
        const float* tb = table + (size_t)l * (TBL * 2);
        float a0 = 0.0f, a1 = 0.0f;
#pragma unroll
        for (int c = 0; c < 8; ++c) {
            const unsigned cx = x0 + (c & 1);
            const unsigned cy = y0 + ((c >> 1) & 1);
            const unsigned cz = z0 + ((c >> 2) & 1);
            unsigned idx;
            if (l < 5) {
                const unsigned s = res + 1u;
                idx = cx + cy * s + cz * (s * s);
            } else {
                idx = (cx * 1u) ^ (cy * 2654435761u) ^ (cz * 805459861u);
                idx &= (unsigned)(TBL - 1);
            }
            const float w = ((c & 1) ? wx : 1.0f - wx) *
                            ((c & 2) ? wy : 1.0f - wy) *
                            ((c & 4) ? wz : 1.0f - wz);
            const float2 f = *reinterpret_cast<const float2*>(tb + 2u * idx);
            a0 = fmaf(f.x, w, a0);
            a1 = fmaf(f.y, w, a1);
        }
        enc[2 * l + 0] = a0;
        enc[2 * l + 1] = a1;
    }

    float h[64];
#pragma unroll
    for (int j = 0; j < 64; ++j) h[j] = 0.0f;
#pragma unroll
    for (int k = 0; k < 32; ++k) {
        const float e = enc[k];
#pragma unroll
        for (int j = 0; j < 64; ++j) h[j] = fmaf(e, ws1[k * 64 + j], h[j]);
    }
#pragma unroll
    for (int j = 0; j < 64; ++j) h[j] = relu_f(h[j]);

    float geo[17];
#pragma unroll
    for (int j = 0; j < 17; ++j) geo[j] = 0.0f;
#pragma unroll
    for (int k = 0; k < 64; ++k) {
        const float e = h[k];
#pragma unroll
        for (int j = 0; j < 17; ++j) geo[j] = fmaf(e, ws2[k * 17 + j], geo[j]);
    }
    out[3 * (size_t)n + (size_t)i] = relu_f(geo[0]);

    const float dx = dirv[3 * (size_t)i + 0] * 2.0f - 1.0f;
    const float dy = dirv[3 * (size_t)i + 1] * 2.0f - 1.0f;
    const float dz = dirv[3 * (size_t)i + 2] * 2.0f - 1.0f;
    const float x2 = dx * dx, y2 = dy * dy, z2 = dz * dz;
    const float xy = dx * dy, yz = dy * dz, xz = dx * dz;

    float sh[16];
    sh[0]  = 0.28209479177387814f;
    sh[1]  = -0.48860251190291987f * dy;
    sh[2]  = 0.48860251190291987f * dz;
    sh[3]  = -0.48860251190291987f * dx;
    sh[4]  = 1.0925484305920792f * xy;
    sh[5]  = -1.0925484305920792f * yz;
    sh[6]  = 0.94617469575756f * z2 - 0.31539156525252f;
    sh[7]  = -1.0925484305920792f * xz;
    sh[8]  = 0.5462742152960396f * (x2 - y2);
    sh[9]  = 0.5900435899266435f * dy * (-3.0f * x2 + y2);
    sh[10] = 2.890611442640554f * xy * dz;
    sh[11] = 0.4570457994644657f * dy * (1.0f - 5.0f * z2);
    sh[12] = 0.3731763325901154f * dz * (5.0f * z2 - 3.0f);
    sh[13] = 0.4570457994644657f * dx * (1.0f - 5.0f * z2);
    sh[14] = 1.445305721320277f * dz * (x2 - y2);
    sh[15] = 0.5900435899266435f * dx * (-x2 + 3.0f * y2);

    float g[64];
#pragma unroll
    for (int j = 0; j < 64; ++j) g[j] = 0.0f;
#pragma unroll
    for (int k = 0; k < 16; ++k) {
        const float e = sh[k];
#pragma unroll
        for (int j = 0; j < 64; ++j) g[j] = fmaf(e, wr1[k * 64 + j], g[j]);
    }
#pragma unroll
    for (int k = 16; k < 32; ++k) {
        const float e = geo[k - 15];
#pragma unroll
        for (int j = 0; j < 64; ++j) g[j] = fmaf(e, wr1[k * 64 + j], g[j]);
    }
#pragma unroll
    for (int j = 0; j < 64; ++j) g[j] = relu_f(g[j]);

    float r0 = 0.0f, r1 = 0.0f, r2 = 0.0f;
#pragma unroll
    for (int half = 0; half < 2; ++half) {
        const int j0 = half * 32;
        float g2h[32];
#pragma unroll
        for (int j = 0; j < 32; ++j) g2h[j] = 0.0f;
#pragma unroll
        for (int k = 0; k < 64; ++k) {
            const float e = g[k];
#pragma unroll
            for (int j = 0; j < 32; ++j) g2h[j] = fmaf(e, wr2[k * 64 + j0 + j], g2h[j]);
        }
#pragma unroll
        for (int j = 0; j < 32; ++j) {
            const float e = relu_f(g2h[j]);
            r0 = fmaf(e, wr3[(j0 + j) * 3 + 0], r0);
            r1 = fmaf(e, wr3[(j0 + j) * 3 + 1], r1);
            r2 = fmaf(e, wr3[(j0 + j) * 3 + 2], r2);
        }
    }

    out[3 * (size_t)i + 0] = 1.0f / (1.0f + __expf(-r0));
    out[3 * (size_t)i + 1] = 1.0f / (1.0f + __expf(-r1));
    out[3 * (size_t)i + 2] = 1.0f / (1.0f + __expf(-r2));
}

extern "C" void kernel_launch(void* const* d_in, const int* in_sizes, int n_in,
                              void* d_out, int out_size, void* d_ws, size_t ws_size,
                              hipStream_t stream)
{
    const float* xyz   = (const float*)d_in[0];
    const float* dirv  = (const float*)d_in[1];
    const float* table = (const float*)d_in[2];
    const float* ws1   = (const float*)d_in[3];
    const float* ws2   = (const float*)d_in[4];
    const float* wr1   = (const float*)d_in[5];
    const float* wr2   = (const float*)d_in[6];
    const float* wr3   = (const float*)d_in[7];
    float* out = (float*)d_out;

    const int n = in_sizes[0] / 3;
    const int blocks_per_level = (n + 255) / 256;
    dim3 block(256);
    dim3 grid_mlp(blocks_per_level);

    const size_t enc_bytes = (size_t)n * 16 * sizeof(unsigned);   // 134 MB at n=2^21
    if (ws_size >= enc_bytes && n >= 2048 && (n & 2047) == 0) {
        unsigned* ws_enc = (unsigned*)d_ws;
        // 16 level-units per XCD, each XCD owns its eighth of the points
        dim3 grid_enc(8u * 16u * (unsigned)(n >> 11));
        hipLaunchKernelGGL(encode_sched, grid_enc, block, 0, stream,
                           xyz, table, ws_enc, n);
        hipLaunchKernelGGL(mlp_mfma, grid_mlp, block, 0, stream,
                           ws_enc, dirv, ws1, ws2, wr1, wr2, wr3, out, n);
    } else {
        hipLaunchKernelGGL(nerf_fused, grid_mlp, block, 0, stream,
                           xyz, dirv, table, ws1, ws2, wr1, wr2, wr3, out, n);
    }
}

// Round 6
// 965.026 us; speedup vs baseline: 1.1473x; 1.0178x over previous
//
#include <hip/hip_runtime.h>
#include <hip/hip_bf16.h>
#include <cmath>

#define TBL (1 << 19)   // T = 2^19 hash table entries per level (power of two)

__device__ __forceinline__ float relu_f(float x) { return fmaxf(x, 0.0f); }

// fp32 -> bf16 bits, round-to-nearest-even
__device__ __forceinline__ unsigned short f2bf(float x) {
    union { float f; unsigned u; } v; v.f = x;
    const unsigned r = v.u + 0x7FFFu + ((v.u >> 16) & 1u);
    return (unsigned short)(r >> 16);
}

typedef __attribute__((ext_vector_type(8))) short short8;   // 8 bf16 = 4 VGPRs (A/B frag)
typedef __attribute__((ext_vector_type(4))) float floatx4;  // C/D frag

// res_l = floor(16 * 1.3819^l); dense iff (res+1)^3 <= 2^19  (l = 0..4)
#define RES_LIST {16, 22, 30, 42, 58, 80, 111, 153, 212, 294, 406, 561, 775, 1072, 1481, 2047}

// ---------------------------------------------------------------------------
// Symmetric scheduled encode (unchanged from round 5 — at its request-rate
// model ceiling: ~210M L2 line-requests @ ~0.5 req/cy/CU => ~690us).
// Every XCD processes its own eighth of the points for every level,
// sequentially -> identical work mix -> balance under any cost model.
// Request cuts: hashed even-x0 float4 pairing (PRIMES[0]==1 =>
// idx(x0+1)=idx(x0)^1), dense parity pairing, packed-bf16 output.
// ---------------------------------------------------------------------------
__global__ __launch_bounds__(256, 8)
void encode_sched(const float* __restrict__ xyz,
                  const float* __restrict__ table,
                  unsigned* __restrict__ ws_enc,   // u32 = 2 bf16, [level*n + i]
                  int n)
{
    constexpr unsigned RES[16] = RES_LIST;
    constexpr int LEVORD[16] = {5, 0, 6, 1, 7, 2, 8, 3, 9, 4, 10, 11, 12, 13, 14, 15};

    const int xcd      = (int)(blockIdx.x & 7u);
    const unsigned g   = blockIdx.x >> 3;
    const unsigned upb = (unsigned)(n >> 11);     // blocks per (xcd, level) phase
    const int unit     = (int)(g / upb);
    const int slot     = (int)(g % upb);
    const int level    = LEVORD[unit & 15];
    const int i        = xcd * (n >> 3) + slot * 256 + (int)threadIdx.x;
    if (i >= n) return;

    const float px_ = __builtin_nontemporal_load(xyz + 3 * (size_t)i + 0);
    const float py_ = __builtin_nontemporal_load(xyz + 3 * (size_t)i + 1);
    const float pz_ = __builtin_nontemporal_load(xyz + 3 * (size_t)i + 2);

    const unsigned res = RES[level];
    const float fr = (float)res;
    const float posx = px_ * fr, posy = py_ * fr, posz = pz_ * fr;
    const float fx = floorf(posx), fy = floorf(posy), fz = floorf(posz);
    const float wx = posx - fx, wy = posy - fy, wz = posz - fz;
    const unsigned x0 = (unsigned)fx, y0 = (unsigned)fy, z0 = (unsigned)fz;
    const float* tb = table + (size_t)level * (TBL * 2);

    float a0 = 0.0f, a1 = 0.0f;
    const float wx1 = wx, wx0 = 1.0f - wx;

    if (level < 5) {
        const unsigned s = res + 1u;
        const unsigned s2 = s * s;
        const unsigned base = x0 + y0 * s + z0 * s2;
#pragma unroll
        for (int c = 0; c < 4; ++c) {
            const unsigned dy = c & 1, dz = c >> 1;
            const unsigned idx = base + dy * s + dz * s2;
            const float wyz = (dy ? wy : 1.0f - wy) * (dz ? wz : 1.0f - wz);
            const float w0 = wyz * wx0, w1 = wyz * wx1;
            float e0x, e0y, e1x, e1y;
            if (!(idx & 1u)) {
                // even idx: entries idx, idx+1 in one aligned 16B slot
                const float4 f = *reinterpret_cast<const float4*>(tb + 2u * idx);
                e0x = f.x; e0y = f.y; e1x = f.z; e1y = f.w;
            } else {
                const float2 f0 = *reinterpret_cast<const float2*>(tb + 2u * idx);
                const float2 f1 = *reinterpret_cast<const float2*>(tb + 2u * idx + 2u);
                e0x = f0.x; e0y = f0.y; e1x = f1.x; e1y = f1.y;
            }
            a0 = fmaf(e0x, w0, fmaf(e1x, w1, a0));
            a1 = fmaf(e0y, w0, fmaf(e1y, w1, a1));
        }
    } else {
#pragma unroll
        for (int c = 0; c < 4; ++c) {
            const unsigned dy = c & 1, dz = c >> 1;
            const unsigned hh = (y0 + dy) * 2654435761u ^ (z0 + dz) * 805459861u;
            const float wyz = (dy ? wy : 1.0f - wy) * (dz ? wz : 1.0f - wz);
            const float w0 = wyz * wx0, w1 = wyz * wx1;
            const unsigned i0 = (x0 ^ hh) & (unsigned)(TBL - 1);
            if (!(x0 & 1u)) {
                // x0 even: idx(x0+1) = i0^1 -> one aligned 16B slot
                const float4 f = *reinterpret_cast<const float4*>(tb + 2u * (i0 & ~1u));
                const bool hi = (i0 & 1u) != 0u;       // position of the x0 entry
                const float e0x = hi ? f.z : f.x, e0y = hi ? f.w : f.y;
                const float e1x = hi ? f.x : f.z, e1y = hi ? f.y : f.w;
                a0 = fmaf(e0x, w0, fmaf(e1x, w1, a0));
                a1 = fmaf(e0y, w0, fmaf(e1y, w1, a1));
            } else {
                const unsigned i1 = ((x0 + 1u) ^ hh) & (unsigned)(TBL - 1);
                const float2 f0 = *reinterpret_cast<const float2*>(tb + 2u * i0);
                const float2 f1 = *reinterpret_cast<const float2*>(tb + 2u * i1);
                a0 = fmaf(f0.x, w0, fmaf(f1.x, w1, a0));
                a1 = fmaf(f0.y, w0, fmaf(f1.y, w1, a1));
            }
        }
    }

    const unsigned pack = (unsigned)f2bf(a0) | ((unsigned)f2bf(a1) << 16);
    __builtin_nontemporal_store(pack, ws_enc + ((size_t)level * n + i));
}

// ---------------------------------------------------------------------------
// MFMA MLP. Round-5 lesson: per-block weight-staging prologue (38KB global +
// 9.5K f2bf, serial at block start, 11 rounds/CU) dominates — MFMA is only
// ~23us of the 288us. Fix: 1024 points per block (wave owns 256 pts = 16
// mt-tiles), grid 8192->2048: staging amortized 4x, rounds/CU 11->3.
// launch_bounds(256,3): VGPR<=168 so LDS (40.7KB) keeps 3 blocks/CU.
// Depth-1 prefetch of next mt's enc+dirv kept.
// ---------------------------------------------------------------------------
__global__ __launch_bounds__(256, 3)
void mlp_mfma(const unsigned* __restrict__ ws_enc,
              const float* __restrict__ dirv,
              const float* __restrict__ ws1,   // (32,64)
              const float* __restrict__ ws2,   // (64,17)
              const float* __restrict__ wr1,   // (32,64)
              const float* __restrict__ wr2,   // (64,64)
              const float* __restrict__ wr3,   // (64,3)
              float* __restrict__ out,
              int n)
{
    __shared__ alignas(16) unsigned short s_w[13184];
    __shared__ alignas(16) unsigned short s_act[4 * 16 * 72];
    __shared__ alignas(16) float          s_geo[4 * 16 * 20];

    const int tid = threadIdx.x;

    for (int e = tid; e < 13184; e += 256) s_w[e] = 0;
    __syncthreads();
    for (int e = tid; e < 2048; e += 256) { const int k = e >> 6, j = e & 63; s_w[0     + j * 40 + k] = f2bf(ws1[e]); }
    for (int e = tid; e < 1088; e += 256) { const int k = e / 17, j = e % 17; s_w[2560  + j * 72 + k] = f2bf(ws2[e]); }
    for (int e = tid; e < 2048; e += 256) { const int k = e >> 6, j = e & 63; s_w[4864  + j * 40 + k] = f2bf(wr1[e]); }
    for (int e = tid; e < 4096; e += 256) { const int k = e >> 6, j = e & 63; s_w[7424  + j * 72 + k] = f2bf(wr2[e]); }
    for (int e = tid; e < 192;  e += 256) { const int k = e / 3,  j = e % 3;  s_w[12032 + j * 72 + k] = f2bf(wr3[e]); }
    __syncthreads();

    const int wave = tid >> 6;
    const int lane = tid & 63;
    const int q    = lane >> 4;
    const int mr   = lane & 15;
    unsigned short* hb = s_act + wave * (16 * 72);
    float*          gb = s_geo + wave * (16 * 20);
    const int base = blockIdx.x * 1024 + wave * 256;
    if (base >= n) return;

    const int pt0 = base + mr;
    // prime mt=0 prefetch
    unsigned e0 = ws_enc[(size_t)(q * 4 + 0) * n + pt0];
    unsigned e1 = ws_enc[(size_t)(q * 4 + 1) * n + pt0];
    unsigned e2 = ws_enc[(size_t)(q * 4 + 2) * n + pt0];
    unsigned e3 = ws_enc[(size_t)(q * 4 + 3) * n + pt0];
    float dv0 = dirv[3 * (size_t)pt0 + 0];
    float dv1 = dirv[3 * (size_t)pt0 + 1];
    float dv2 = dirv[3 * (size_t)pt0 + 2];

#pragma unroll 1
    for (int mt = 0; mt < 16; ++mt) {
        // ---- issue next-mt global loads early (hidden under compute below)
        unsigned f0 = 0, f1 = 0, f2 = 0, f3 = 0;
        float c0 = 0.f, c1 = 0.f, c2 = 0.f;
        if (mt < 15) {
            const int ptn = pt0 + (mt + 1) * 16;
            f0 = ws_enc[(size_t)(q * 4 + 0) * n + ptn];
            f1 = ws_enc[(size_t)(q * 4 + 1) * n + ptn];
            f2 = ws_enc[(size_t)(q * 4 + 2) * n + ptn];
            f3 = ws_enc[(size_t)(q * 4 + 3) * n + ptn];
            c0 = dirv[3 * (size_t)ptn + 0];
            c1 = dirv[3 * (size_t)ptn + 1];
            c2 = dirv[3 * (size_t)ptn + 2];
        }

        // ---- enc A-fragment from prefetched registers
        short8 aenc;
        aenc[0] = (short)(e0 & 0xFFFFu); aenc[1] = (short)(e0 >> 16);
        aenc[2] = (short)(e1 & 0xFFFFu); aenc[3] = (short)(e1 >> 16);
        aenc[4] = (short)(e2 & 0xFFFFu); aenc[5] = (short)(e2 >> 16);
        aenc[6] = (short)(e3 & 0xFFFFu); aenc[7] = (short)(e3 >> 16);

#pragma unroll
        for (int nc = 0; nc < 4; ++nc) {
            const short8 b = *reinterpret_cast<const short8*>(s_w + 0 + (nc * 16 + mr) * 40 + q * 8);
            floatx4 acc = {0.f, 0.f, 0.f, 0.f};
            acc = __builtin_amdgcn_mfma_f32_16x16x32_bf16(aenc, b, acc, 0, 0, 0);
#pragma unroll
            for (int r = 0; r < 4; ++r)
                hb[(q * 4 + r) * 72 + nc * 16 + mr] = f2bf(fmaxf(acc[r], 0.f));
        }
        __builtin_amdgcn_wave_barrier();

        {
            const short8 a0 = *reinterpret_cast<const short8*>(hb + mr * 72 + 0  + q * 8);
            const short8 a1 = *reinterpret_cast<const short8*>(hb + mr * 72 + 32 + q * 8);
            floatx4 acc0 = {0.f, 0.f, 0.f, 0.f};
            floatx4 acc1 = {0.f, 0.f, 0.f, 0.f};
            {
                const short8 b0 = *reinterpret_cast<const short8*>(s_w + 2560 + mr * 72 + 0  + q * 8);
                const short8 b1 = *reinterpret_cast<const short8*>(s_w + 2560 + mr * 72 + 32 + q * 8);
                acc0 = __builtin_amdgcn_mfma_f32_16x16x32_bf16(a0, b0, acc0, 0, 0, 0);
                acc0 = __builtin_amdgcn_mfma_f32_16x16x32_bf16(a1, b1, acc0, 0, 0, 0);
            }
            {
                const short8 b0 = *reinterpret_cast<const short8*>(s_w + 2560 + (16 + mr) * 72 + 0  + q * 8);
                const short8 b1 = *reinterpret_cast<const short8*>(s_w + 2560 + (16 + mr) * 72 + 32 + q * 8);
                acc1 = __builtin_amdgcn_mfma_f32_16x16x32_bf16(a0, b0, acc1, 0, 0, 0);
                acc1 = __builtin_amdgcn_mfma_f32_16x16x32_bf16(a1, b1, acc1, 0, 0, 0);
            }
#pragma unroll
            for (int r = 0; r < 4; ++r) gb[(q * 4 + r) * 20 + mr + 3] = acc0[r];
            if (mr == 0) {
#pragma unroll
                for (int r = 0; r < 4; ++r) gb[(q * 4 + r) * 20 + 19] = acc1[r];
            }
        }
        __builtin_amdgcn_wave_barrier();

        if (lane < 16)
            out[3 * (size_t)n + (size_t)(base + mt * 16 + lane)] = fmaxf(gb[lane * 20 + 3], 0.f);

        // ---- SH deg-4 from prefetched dirv
        const float dx = dv0 * 2.0f - 1.0f;
        const float dy = dv1 * 2.0f - 1.0f;
        const float dz = dv2 * 2.0f - 1.0f;
        const float x2 = dx * dx, y2 = dy * dy, z2 = dz * dz;
        const float xy = dx * dy, yz = dy * dz, xz = dx * dz;
        float sh[16];
        sh[0]  = 0.28209479177387814f;
        sh[1]  = -0.48860251190291987f * dy;
        sh[2]  = 0.48860251190291987f * dz;
        sh[3]  = -0.48860251190291987f * dx;
        sh[4]  = 1.0925484305920792f * xy;
        sh[5]  = -1.0925484305920792f * yz;
        sh[6]  = 0.94617469575756f * z2 - 0.31539156525252f;
        sh[7]  = -1.0925484305920792f * xz;
        sh[8]  = 0.5462742152960396f * (x2 - y2);
        sh[9]  = 0.5900435899266435f * dy * (-3.0f * x2 + y2);
        sh[10] = 2.890611442640554f * xy * dz;
        sh[11] = 0.4570457994644657f * dy * (1.0f - 5.0f * z2);
        sh[12] = 0.3731763325901154f * dz * (5.0f * z2 - 3.0f);
        sh[13] = 0.4570457994644657f * dx * (1.0f - 5.0f * z2);
        sh[14] = 1.445305721320277f * dz * (x2 - y2);
        sh[15] = 0.5900435899266435f * dx * (-x2 + 3.0f * y2);

        short8 ar;
        if (q < 2) {
#pragma unroll
            for (int j = 0; j < 8; ++j) ar[j] = (short)f2bf(sh[q * 8 + j]);
        } else {
            const floatx4 g0 = *reinterpret_cast<const floatx4*>(gb + mr * 20 + 4 + (q - 2) * 8);
            const floatx4 g1 = *reinterpret_cast<const floatx4*>(gb + mr * 20 + 8 + (q - 2) * 8);
#pragma unroll
            for (int j = 0; j < 4; ++j) { ar[j] = (short)f2bf(g0[j]); ar[4 + j] = (short)f2bf(g1[j]); }
        }

#pragma unroll
        for (int nc = 0; nc < 4; ++nc) {
            const short8 b = *reinterpret_cast<const short8*>(s_w + 4864 + (nc * 16 + mr) * 40 + q * 8);
            floatx4 acc = {0.f, 0.f, 0.f, 0.f};
            acc = __builtin_amdgcn_mfma_f32_16x16x32_bf16(ar, b, acc, 0, 0, 0);
#pragma unroll
            for (int r = 0; r < 4; ++r)
                hb[(q * 4 + r) * 72 + nc * 16 + mr] = f2bf(fmaxf(acc[r], 0.f));
        }
        __builtin_amdgcn_wave_barrier();

        {
            const short8 a0 = *reinterpret_cast<const short8*>(hb + mr * 72 + 0  + q * 8);
            const short8 a1 = *reinterpret_cast<const short8*>(hb + mr * 72 + 32 + q * 8);
            __builtin_amdgcn_wave_barrier();
#pragma unroll
            for (int nc = 0; nc < 4; ++nc) {
                const short8 b0 = *reinterpret_cast<const short8*>(s_w + 7424 + (nc * 16 + mr) * 72 + 0  + q * 8);
                const short8 b1 = *reinterpret_cast<const short8*>(s_w + 7424 + (nc * 16 + mr) * 72 + 32 + q * 8);
                floatx4 acc = {0.f, 0.f, 0.f, 0.f};
                acc = __builtin_amdgcn_mfma_f32_16x16x32_bf16(a0, b0, acc, 0, 0, 0);
                acc = __builtin_amdgcn_mfma_f32_16x16x32_bf16(a1, b1, acc, 0, 0, 0);
#pragma unroll
                for (int r = 0; r < 4; ++r)
                    hb[(q * 4 + r) * 72 + nc * 16 + mr] = f2bf(fmaxf(acc[r], 0.f));
            }
        }
        __builtin_amdgcn_wave_barrier();

        {
            const short8 a0 = *reinterpret_cast<const short8*>(hb + mr * 72 + 0  + q * 8);
            const short8 a1 = *reinterpret_cast<const short8*>(hb + mr * 72 + 32 + q * 8);
            const short8 b0 = *reinterpret_cast<const short8*>(s_w + 12032 + mr * 72 + 0  + q * 8);
            const short8 b1 = *reinterpret_cast<const short8*>(s_w + 12032 + mr * 72 + 32 + q * 8);
            floatx4 acc = {0.f, 0.f, 0.f, 0.f};
            acc = __builtin_amdgcn_mfma_f32_16x16x32_bf16(a0, b0, acc, 0, 0, 0);
            acc = __builtin_amdgcn_mfma_f32_16x16x32_bf16(a1, b1, acc, 0, 0, 0);
            if (mr < 3) {
#pragma unroll
                for (int r = 0; r < 4; ++r) {
                    const int p = base + mt * 16 + q * 4 + r;
                    out[3 * (size_t)p + mr] = 1.0f / (1.0f + __expf(-acc[r]));
                }
            }
        }
        __builtin_amdgcn_wave_barrier();

        e0 = f0; e1 = f1; e2 = f2; e3 = f3;
        dv0 = c0; dv1 = c1; dv2 = c2;
    }
}

// ---------------------------------------------------------------------------
// Fallback: fused kernel (used only if ws can't hold enc or n % 2048 != 0).
// ---------------------------------------------------------------------------
__global__ __launch_bounds__(256, 4)
void nerf_fused(const float* __restrict__ xyz,
                const float* __restrict__ dirv,
                const float* __restrict__ table,
                const float* __restrict__ ws1,
                const float* __restrict__ ws2,
                const float* __restrict__ wr1,
                const float* __restrict__ wr2,
                const float* __restrict__ wr3,
                float* __restrict__ out,
                int n)
{
    constexpr unsigned RES[16] = RES_LIST;

    const int i = blockIdx.x * 256 + threadIdx.x;
    if (i >= n) return;

    const float px_ = xyz[3 * (size_t)i + 0];
    const float py_ = xyz[3 * (size_t)i + 1];
    const float pz_ = xyz[3 * (size_t)i + 2];

    float enc[32];
#pragma unroll
    for (int l = 0; l < 16; ++l) {
        const unsigned res = RES[l];
        const float fr = (float)res;
        const float posx = px_ * fr, posy = py_ * fr, posz = pz_ * fr;
        const float fx = floorf(posx), fy = floorf(posy), fz = floorf(posz);
        const float wx = posx - fx, wy = posy - fy, wz = posz - fz;
        const unsigned x0 = (unsigned)fx, y0 = (unsigned)fy, z0 = (unsigned)fz;
        const float* tb = table + (size_t)l * (TBL * 2);
        float a0 = 0.0f, a1 = 0.0f;
#pragma unroll
        for (int c = 0; c < 8; ++c) {
            const unsigned cx = x0 + (c & 1);
            const unsigned cy = y0 + ((c >> 1) & 1);
            const unsigned cz = z0 + ((c >> 2) & 1);
            unsigned idx;
            if (l < 5) {
                const unsigned s = res + 1u;
                idx = cx + cy * s + cz * (s * s);
            } else {
                idx = (cx * 1u) ^ (cy * 2654435761u) ^ (cz * 805459861u);
                idx &= (unsigned)(TBL - 1);
            }
            const float w = ((c & 1) ? wx : 1.0f - wx) *
                            ((c & 2) ? wy : 1.0f - wy) *
                            ((c & 4) ? wz : 1.0f - wz);
            const float2 f = *reinterpret_cast<const float2*>(tb + 2u * idx);
            a0 = fmaf(f.x, w, a0);
            a1 = fmaf(f.y, w, a1);
        }
        enc[2 * l + 0] = a0;
        enc[2 * l + 1] = a1;
    }

    float h[64];
#pragma unroll
    for (int j = 0; j < 64; ++j) h[j] = 0.0f;
#pragma unroll
    for (int k = 0; k < 32; ++k) {
        const float e = enc[k];
#pragma unroll
        for (int j = 0; j < 64; ++j) h[j] = fmaf(e, ws1[k * 64 + j], h[j]);
    }
#pragma unroll
    for (int j = 0; j < 64; ++j) h[j] = relu_f(h[j]);

    float geo[17];
#pragma unroll
    for (int j = 0; j < 17; ++j) geo[j] = 0.0f;
#pragma unroll
    for (int k = 0; k < 64; ++k) {
        const float e = h[k];
#pragma unroll
        for (int j = 0; j < 17; ++j) geo[j] = fmaf(e, ws2[k * 17 + j], geo[j]);
    }
    out[3 * (size_t)n + (size_t)i] = relu_f(geo[0]);

    const float dx = dirv[3 * (size_t)i + 0] * 2.0f - 1.0f;
    const float dy = dirv[3 * (size_t)i + 1] * 2.0f - 1.0f;
    const float dz = dirv[3 * (size_t)i + 2] * 2.0f - 1.0f;
    const float x2 = dx * dx, y2 = dy * dy, z2 = dz * dz;
    const float xy = dx * dy, yz = dy * dz, xz = dx * dz;

    float sh[16];
    sh[0]  = 0.28209479177387814f;
    sh[1]  = -0.48860251190291987f * dy;
    sh[2]  = 0.48860251190291987f * dz;
    sh[3]  = -0.48860251190291987f * dx;
    sh[4]  = 1.0925484305920792f * xy;
    sh[5]  = -1.0925484305920792f * yz;
    sh[6]  = 0.94617469575756f * z2 - 0.31539156525252f;
    sh[7]  = -1.0925484305920792f * xz;
    sh[8]  = 0.5462742152960396f * (x2 - y2);
    sh[9]  = 0.5900435899266435f * dy * (-3.0f * x2 + y2);
    sh[10] = 2.890611442640554f * xy * dz;
    sh[11] = 0.4570457994644657f * dy * (1.0f - 5.0f * z2);
    sh[12] = 0.3731763325901154f * dz * (5.0f * z2 - 3.0f);
    sh[13] = 0.4570457994644657f * dx * (1.0f - 5.0f * z2);
    sh[14] = 1.445305721320277f * dz * (x2 - y2);
    sh[15] = 0.5900435899266435f * dx * (-x2 + 3.0f * y2);

    float g[64];
#pragma unroll
    for (int j = 0; j < 64; ++j) g[j] = 0.0f;
#pragma unroll
    for (int k = 0; k < 16; ++k) {
        const float e = sh[k];
#pragma unroll
        for (int j = 0; j < 64; ++j) g[j] = fmaf(e, wr1[k * 64 + j], g[j]);
    }
#pragma unroll
    for (int k = 16; k < 32; ++k) {
        const float e = geo[k - 15];
#pragma unroll
        for (int j = 0; j < 64; ++j) g[j] = fmaf(e, wr1[k * 64 + j], g[j]);
    }
#pragma unroll
    for (int j = 0; j < 64; ++j) g[j] = relu_f(g[j]);

    float r0 = 0.0f, r1 = 0.0f, r2 = 0.0f;
#pragma unroll
    for (int half = 0; half < 2; ++half) {
        const int j0 = half * 32;
        float g2h[32];
#pragma unroll
        for (int j = 0; j < 32; ++j) g2h[j] = 0.0f;
#pragma unroll
        for (int k = 0; k < 64; ++k) {
            const float e = g[k];
#pragma unroll
            for (int j = 0; j < 32; ++j) g2h[j] = fmaf(e, wr2[k * 64 + j0 + j], g2h[j]);
        }
#pragma unroll
        for (int j = 0; j < 32; ++j) {
            const float e = relu_f(g2h[j]);
            r0 = fmaf(e, wr3[(j0 + j) * 3 + 0], r0);
            r1 = fmaf(e, wr3[(j0 + j) * 3 + 1], r1);
            r2 = fmaf(e, wr3[(j0 + j) * 3 + 2], r2);
        }
    }

    out[3 * (size_t)i + 0] = 1.0f / (1.0f + __expf(-r0));
    out[3 * (size_t)i + 1] = 1.0f / (1.0f + __expf(-r1));
    out[3 * (size_t)i + 2] = 1.0f / (1.0f + __expf(-r2));
}

extern "C" void kernel_launch(void* const* d_in, const int* in_sizes, int n_in,
                              void* d_out, int out_size, void* d_ws, size_t ws_size,
                              hipStream_t stream)
{
    const float* xyz   = (const float*)d_in[0];
    const float* dirv  = (const float*)d_in[1];
    const float* table = (const float*)d_in[2];
    const float* ws1   = (const float*)d_in[3];
    const float* ws2   = (const float*)d_in[4];
    const float* wr1   = (const float*)d_in[5];
    const float* wr2   = (const float*)d_in[6];
    const float* wr3   = (const float*)d_in[7];
    float* out = (float*)d_out;

    const int n = in_sizes[0] / 3;
    dim3 block(256);

    const size_t enc_bytes = (size_t)n * 16 * sizeof(unsigned);   // 134 MB at n=2^21
    if (ws_size >= enc_bytes && n >= 2048 && (n & 2047) == 0) {
        unsigned* ws_enc = (unsigned*)d_ws;
        // 16 level-units per XCD, each XCD owns its eighth of the points
        dim3 grid_enc(8u * 16u * (unsigned)(n >> 11));
        dim3 grid_mlp((unsigned)(n >> 10));   // 1024 points per block
        hipLaunchKernelGGL(encode_sched, grid_enc, block, 0, stream,
                           xyz, table, ws_enc, n);
        hipLaunchKernelGGL(mlp_mfma, grid_mlp, block, 0, stream,
                           ws_enc, dirv, ws1, ws2, wr1, wr2, wr3, out, n);
    } else {
        dim3 grid_mlp((n + 255) / 256);
        hipLaunchKernelGGL(nerf_fused, grid_mlp, block, 0, stream,
                           xyz, dirv, table, ws1, ws2, wr1, wr2, wr3, out, n);
    }
}